// Round 15
// baseline (121.355 us; speedup 1.0000x reference)
//
#include <hip/hip_runtime.h>
#include <stdint.h>

// CrossAttentionLayer: B=2, Q=256, N=16384, C=256, H=8, d=32
#define B_ 2
#define Q_ 256
#define N_ 16384
#define C_ 256
#define H_ 8
#define D_ 32
#define NC_ 32                       // attention split-N chunks (512 keys/block)
#define SCALEQ 0.2550542176432015f   // (1/sqrt(32)) * log2(e)  [exp -> exp2]

typedef __bf16 bf16x8 __attribute__((ext_vector_type(8)));
typedef float f32x4 __attribute__((ext_vector_type(4)));

__device__ __forceinline__ uint16_t bfbits(float f) {
  union { __bf16 h; uint16_t u; } c; c.h = (__bf16)f; return c.u;
}
__device__ __forceinline__ float bf2f(uint16_t u) {
  union { uint32_t u; float f; } c; c.u = (uint32_t)u << 16;
  return c.f;
}
__device__ __forceinline__ uint32_t pk2(float a, float b) {
  union { struct { uint16_t lo, hi; } s; uint32_t u; } c;
  c.s.lo = bfbits(a); c.s.hi = bfbits(b);
  return c.u;  // fuses to v_cvt_pk_bf16_f32
}
__device__ __forceinline__ void lgkm0_barrier() {
  __builtin_amdgcn_sched_barrier(0);
  asm volatile("s_waitcnt lgkmcnt(0)" ::: "memory");
  __builtin_amdgcn_sched_barrier(0);
  __builtin_amdgcn_s_barrier();
  __builtin_amdgcn_sched_barrier(0);
}

// ---------------------------------------------------------------------------
// Kernel 1 "prep" (small): blocks 0..95: in_proj_w -> bf16; 96..159: woT.
// (mask-pack moved into kvqproj as interleaved blocks)
// ---------------------------------------------------------------------------
__global__ __launch_bounds__(256) void prep(const float* __restrict__ inw,
                                            const float* __restrict__ outw,
                                            uint16_t* __restrict__ wb,
                                            float* __restrict__ woT) {
  __shared__ float s[32][33];
  const int bid = blockIdx.x;
  const int t = threadIdx.x;
  if (bid < 96) {
    const int i = (bid * 256 + t) * 8;
    const float4 a = *reinterpret_cast<const float4*>(inw + i);
    const float4 b = *reinterpret_cast<const float4*>(inw + i + 4);
    ushort4 lo = {bfbits(a.x), bfbits(a.y), bfbits(a.z), bfbits(a.w)};
    ushort4 hi = {bfbits(b.x), bfbits(b.y), bfbits(b.z), bfbits(b.w)};
    *reinterpret_cast<ushort4*>(wb + i) = lo;
    *reinterpret_cast<ushort4*>(wb + i + 4) = hi;
  } else {
    const int bb = bid - 96;
    const int bx = bb & 7, by = bb >> 3;
    const int r0 = by * 32, c0 = bx * 32;
    const int tr = t >> 5, tc = t & 31;
#pragma unroll
    for (int k = 0; k < 4; ++k)
      s[tr + 8 * k][tc] = outw[(size_t)(r0 + tr + 8 * k) * 256 + c0 + tc];
    __syncthreads();
#pragma unroll
    for (int k = 0; k < 4; ++k)
      woT[(size_t)(c0 + tr + 8 * k) * 256 + r0 + tc] = s[tc][tr + 8 * k];
  }
}

// ---------------------------------------------------------------------------
// Kernel 2 "kvqproj" (R14): the verified ~50us KV structure (bf16 wkv
// weights) + mask-pack blocks INTERLEAVED 1:1 with KV blocks.
//  bid 0..7      : Q projection via MFMA
//  bid 8..1031   : pair=bid-8; even -> KV block (pair>>1), odd -> mask block
// KV block: wave w = head w; K+V over 64 n; 2-deep act prefetch; XOR-swizzled
// LDS; lgkm-only barrier. Mask block: pure HBM stream (no barriers coupling
// to KV) -> uses bandwidth KV blocks leave idle.
// Outputs: Kh [b][h][n][32], Vh [b][h][32][n], Qb pre-scaled by SCALEQ.
// ---------------------------------------------------------------------------
__global__ __launch_bounds__(512, 2) void kvqproj(const float* __restrict__ vf,
                                                  const float* __restrict__ pe,
                                                  const float* __restrict__ queries,
                                                  const float* __restrict__ qembed,
                                                  const uint16_t* __restrict__ wkv,
                                                  const float* __restrict__ vm,
                                                  const float* __restrict__ bias,
                                                  uint16_t* __restrict__ Kh,
                                                  uint16_t* __restrict__ Vh,
                                                  uint16_t* __restrict__ Qb,
                                                  uint32_t* __restrict__ mb) {
  __shared__ __align__(16) uint16_t shpool[8][64][40];
  __shared__ int wcnt[8];
  __shared__ int tot;
  const int bid = blockIdx.x;
  const int t = threadIdx.x, wid = t >> 6, lane = t & 63;
  const int g = lane >> 4, c15 = lane & 15;

  if (bid >= 8 && ((bid - 8) & 1) == 0) {
    // ================= KV projection block (verified structure) ============
    const int kb = (bid - 8) >> 1;
    const int b = kb >> 8, nt = kb & 255;
    const int n0 = nt * 64;
    const int w = wid;  // head

    const uint16_t* WsecK = wkv + (size_t)(256 + w * 32 + c15) * C_;
    const uint16_t* WsecV = wkv + (size_t)(512 + w * 32 + c15) * C_;

    f32x4 acck[8];  // [cf*4+nf]: D[row=cout][col=n]
    f32x4 accv[8];  // [nf*2+cf]: D[row=n][col=cout]
#pragma unroll
    for (int cf = 0; cf < 2; ++cf) {
      f32x4 ivk;
#pragma unroll
      for (int j = 0; j < 4; ++j) ivk[j] = bias[256 + w * 32 + cf * 16 + 4 * g + j];
      const float bv = bias[512 + w * 32 + cf * 16 + c15];
      const f32x4 ivv = {bv, bv, bv, bv};
#pragma unroll
      for (int nf = 0; nf < 4; ++nf) {
        acck[cf * 4 + nf] = ivk;
        accv[nf * 2 + cf] = ivv;
      }
    }

    const int cq = t >> 5, q2 = t & 31;
    const float* Xb = vf + ((size_t)b * C_ + 2 * cq) * N_ + n0 + 2 * q2;
    const float* Pb = pe + ((size_t)b * C_ + 2 * cq) * N_ + n0 + 2 * q2;
    const int cqs = cq ^ (((q2 >> 2) & 3) << 2);  // 16B-block XOR swizzle

    float2 xA0, xA1, pA0, pA1, xB0, xB1, pB0, pB1;
    bf16x8 Wk[2], Wv[2];

#define LOADW(s)                                                             \
    {                                                                        \
      _Pragma("unroll") for (int cf = 0; cf < 2; ++cf) {                     \
        Wk[cf] = *(const bf16x8*)(WsecK + (size_t)cf * 16 * C_ + (s) * 32 + g * 8); \
        Wv[cf] = *(const bf16x8*)(WsecV + (size_t)cf * 16 * C_ + (s) * 32 + g * 8); \
      }                                                                      \
    }
#define LOADA(X0, X1, P0, P1, s)                                             \
    {                                                                        \
      const float* x_ = Xb + (size_t)(s) * 32 * N_;                          \
      const float* p_ = Pb + (size_t)(s) * 32 * N_;                          \
      X0 = *(const float2*)x_;                                               \
      X1 = *(const float2*)(x_ + N_);                                        \
      P0 = *(const float2*)p_;                                               \
      P1 = *(const float2*)(p_ + N_);                                        \
    }
#define WRITEA(X0, X1, P0, P1, bufp)                                         \
    {                                                                        \
      *(uint32_t*)&shpool[bufp][2 * q2][2 * cqs]     = pk2(X0.x + P0.x, X1.x + P1.x); \
      *(uint32_t*)&shpool[bufp][2 * q2 + 1][2 * cqs] = pk2(X0.y + P0.y, X1.y + P1.y); \
      *(uint32_t*)&shpool[(bufp) + 1][2 * q2][2 * cqs]     = pk2(X0.x, X1.x); \
      *(uint32_t*)&shpool[(bufp) + 1][2 * q2 + 1][2 * cqs] = pk2(X0.y, X1.y); \
    }
#define COMPUTE(bufp)                                                        \
    {                                                                        \
      _Pragma("unroll") for (int nf = 0; nf < 4; ++nf) {                     \
        const int r_ = nf * 16 + c15;                                        \
        const int o_ = (g ^ ((r_ >> 3) & 3)) * 8;                            \
        const bf16x8 Fp = *(const bf16x8*)&shpool[bufp][r_][o_];             \
        const bf16x8 Fv = *(const bf16x8*)&shpool[(bufp) + 1][r_][o_];       \
        _Pragma("unroll") for (int cf = 0; cf < 2; ++cf) {                   \
          acck[cf * 4 + nf] = __builtin_amdgcn_mfma_f32_16x16x32_bf16(       \
              Wk[cf], Fp, acck[cf * 4 + nf], 0, 0, 0);                       \
          accv[nf * 2 + cf] = __builtin_amdgcn_mfma_f32_16x16x32_bf16(       \
              Fv, Wv[cf], accv[nf * 2 + cf], 0, 0, 0);                       \
        }                                                                    \
      }                                                                      \
    }

    LOADA(xA0, xA1, pA0, pA1, 0);
    LOADA(xB0, xB1, pB0, pB1, 1);
    // s=0
    LOADW(0); WRITEA(xA0, xA1, pA0, pA1, 0); LOADA(xA0, xA1, pA0, pA1, 2);
    lgkm0_barrier(); COMPUTE(0); __builtin_amdgcn_sched_barrier(0);
    // s=1
    LOADW(1); WRITEA(xB0, xB1, pB0, pB1, 2); LOADA(xB0, xB1, pB0, pB1, 3);
    lgkm0_barrier(); COMPUTE(2); __builtin_amdgcn_sched_barrier(0);
    // s=2
    LOADW(2); WRITEA(xA0, xA1, pA0, pA1, 0); LOADA(xA0, xA1, pA0, pA1, 4);
    lgkm0_barrier(); COMPUTE(0); __builtin_amdgcn_sched_barrier(0);
    // s=3
    LOADW(3); WRITEA(xB0, xB1, pB0, pB1, 2); LOADA(xB0, xB1, pB0, pB1, 5);
    lgkm0_barrier(); COMPUTE(2); __builtin_amdgcn_sched_barrier(0);
    // s=4
    LOADW(4); WRITEA(xA0, xA1, pA0, pA1, 0); LOADA(xA0, xA1, pA0, pA1, 6);
    lgkm0_barrier(); COMPUTE(0); __builtin_amdgcn_sched_barrier(0);
    // s=5
    LOADW(5); WRITEA(xB0, xB1, pB0, pB1, 2); LOADA(xB0, xB1, pB0, pB1, 7);
    lgkm0_barrier(); COMPUTE(2); __builtin_amdgcn_sched_barrier(0);
    // s=6
    LOADW(6); WRITEA(xA0, xA1, pA0, pA1, 0);
    lgkm0_barrier(); COMPUTE(0); __builtin_amdgcn_sched_barrier(0);
    // s=7
    LOADW(7); WRITEA(xB0, xB1, pB0, pB1, 2);
    lgkm0_barrier(); COMPUTE(2); __builtin_amdgcn_sched_barrier(0);

#undef LOADW
#undef LOADA
#undef WRITEA
#undef COMPUTE

    uint16_t* Kp = Kh + (size_t)(b * H_ + w) * N_ * D_;
#pragma unroll
    for (int cf = 0; cf < 2; ++cf)
#pragma unroll
      for (int nf = 0; nf < 4; ++nf) {
        const f32x4 a = acck[cf * 4 + nf];
        uint2 pkv;
        pkv.x = pk2(a[0], a[1]);
        pkv.y = pk2(a[2], a[3]);
        *(uint2*)&Kp[(size_t)(n0 + nf * 16 + c15) * D_ + cf * 16 + 4 * g] = pkv;
      }
    uint16_t* Vp = Vh + (size_t)(b * H_ + w) * D_ * N_;
#pragma unroll
    for (int nf = 0; nf < 4; ++nf)
#pragma unroll
      for (int cf = 0; cf < 2; ++cf) {
        const f32x4 a = accv[nf * 2 + cf];
        uint2 pkv;
        pkv.x = pk2(a[0], a[1]);
        pkv.y = pk2(a[2], a[3]);
        *(uint2*)&Vp[(size_t)(cf * 16 + c15) * N_ + n0 + nf * 16 + 4 * g] = pkv;
      }
  } else if (bid >= 8) {
    // ================= mask-pack block (pure HBM stream) ==================
    const int bq = (bid - 8) >> 1;  // 0..511
    uint8_t(*nib)[512] = reinterpret_cast<uint8_t(*)[512]>(&shpool[0][0][0]);
    const float* row = vm + (size_t)bq * N_;
    int cnt = 0;
#pragma unroll
    for (int i = 0; i < 8; ++i) {
      const float4 v = *reinterpret_cast<const float4*>(&row[i * 2048 + 4 * t]);
      const uint32_t nb = (v.x < 0.5f ? 1u : 0u) | (v.y < 0.5f ? 2u : 0u) |
                          (v.z < 0.5f ? 4u : 0u) | (v.w < 0.5f ? 8u : 0u);
      nib[i][t] = (uint8_t)nb;
      cnt += __popc(nb);
    }
    for (int o = 32; o > 0; o >>= 1) cnt += __shfl_down(cnt, o, 64);
    if (lane == 0) wcnt[wid] = cnt;
    __syncthreads();
    if (t == 0) {
      int s = 0;
#pragma unroll
      for (int k = 0; k < 8; ++k) s += wcnt[k];
      tot = s;
    }
    __syncthreads();
    const bool allb = (tot == N_);
    const int w = t;  // one 32-bit word per thread
    const uint2 u = *reinterpret_cast<const uint2*>(&nib[w >> 6][8 * (w & 63)]);
    uint32_t y0 = u.x & 0x0F0F0F0Fu; y0 = y0 | (y0 >> 4);
    uint32_t y1 = u.y & 0x0F0F0F0Fu; y1 = y1 | (y1 >> 4);
    const uint32_t word = (y0 & 0xFFu) | (((y0 >> 16) & 0xFFu) << 8) |
                          ((y1 & 0xFFu) << 16) | (((y1 >> 16) & 0xFFu) << 24);
    mb[(size_t)bq * 512 + w] = allb ? 0u : word;
  } else {
    // ================= Q projection: 8 blocks x 64 q-rows =================
    const int q0g = bid * 64;
    const int b = q0g >> 8, q0 = q0g & 255;
    const int r = t >> 3, c0 = (t & 7) * 32, s = t & 7;
    const float* Qrow = queries + (size_t)(q0g + r) * C_ + c0;
    const float* Erow = qembed + (size_t)(q0g + r) * C_ + c0;
#pragma unroll
    for (int ph = 0; ph < 2; ++ph) {
      float4 a4[4], e4[4];
#pragma unroll
      for (int k = 0; k < 4; ++k) a4[k] = reinterpret_cast<const float4*>(Qrow + ph * 16)[k];
#pragma unroll
      for (int k = 0; k < 4; ++k) e4[k] = reinterpret_cast<const float4*>(Erow + ph * 16)[k];
      const float* af = reinterpret_cast<const float*>(a4);
      const float* ef = reinterpret_cast<const float*>(e4);
#pragma unroll
      for (int i = 0; i < 16; ++i) {
        const int cl = ph * 16 + i;
        const int col = cl ^ (8 * ((r >> 3) & 3));
        shpool[s][r][col] = bfbits(af[i] + ef[i]);
      }
      __builtin_amdgcn_sched_barrier(0);
    }
    lgkm0_barrier();

    const int w = wid;  // head = w
    f32x4 acc[4][2];
#pragma unroll
    for (int nf = 0; nf < 2; ++nf) {
      const float bv = bias[w * 32 + nf * 16 + c15];
      const f32x4 iv = {bv, bv, bv, bv};
#pragma unroll
      for (int qf = 0; qf < 4; ++qf) acc[qf][nf] = iv;
    }
#pragma unroll
    for (int s8 = 0; s8 < 8; ++s8) {
      bf16x8 Bf[2];
#pragma unroll
      for (int nf = 0; nf < 2; ++nf)
        Bf[nf] = *reinterpret_cast<const bf16x8*>(
            wkv + (size_t)(w * 32 + nf * 16 + c15) * C_ + s8 * 32 + g * 8);
#pragma unroll
      for (int qf = 0; qf < 4; ++qf) {
        const int rr = qf * 16 + c15;
        const bf16x8 Af = *reinterpret_cast<const bf16x8*>(
            &shpool[s8][rr][8 * (g ^ ((rr >> 3) & 3))]);
#pragma unroll
        for (int nf = 0; nf < 2; ++nf)
          acc[qf][nf] = __builtin_amdgcn_mfma_f32_16x16x32_bf16(Af, Bf[nf], acc[qf][nf], 0, 0, 0);
      }
    }
#pragma unroll
    for (int qf = 0; qf < 4; ++qf)
#pragma unroll
      for (int nf = 0; nf < 2; ++nf)
#pragma unroll
        for (int j = 0; j < 4; ++j) {
          const int q = q0 + qf * 16 + 4 * g + j;
          const int dk = nf * 16 + c15;
          Qb[((size_t)(b * H_ + w) * Q_ + q) * D_ + dk] = bfbits(acc[qf][nf][j] * SCALEQ);
        }
  }
}

// ---------------------------------------------------------------------------
// Kernel 3: attention over an N-chunk of 512 keys, all 256 queries of one
// (b,h). p = exp2(s) (log2e folded into Q scale). ctx partials bf16.
// ---------------------------------------------------------------------------
__global__ __launch_bounds__(512) void attn(const uint16_t* __restrict__ Qb,
                                            const uint16_t* __restrict__ Kh,
                                            const uint16_t* __restrict__ Vh,
                                            const uint32_t* __restrict__ mb,
                                            uint16_t* __restrict__ ctx_part,
                                            float* __restrict__ lsum_part) {
  const int bid = blockIdx.x;
  const int nc = bid & 31, h = (bid >> 5) & 7, b = bid >> 8;
  const int t = threadIdx.x, wid = t >> 6, lane = t & 63;
  const int g = lane >> 4, c15 = lane & 15;
  const int qw0 = wid * 32;
  const int nbase = nc * (N_ / NC_);
  constexpr int SS = (N_ / NC_) / 128;

  __shared__ __align__(16) uint16_t kst[2][128][40];
  __shared__ __align__(16) uint16_t vst[2][32][136];
  __shared__ __align__(16) uint16_t plds[8][32][40];

  const uint16_t* Qp = Qb + (size_t)(b * H_ + h) * Q_ * D_;
  bf16x8 qfr[2];
#pragma unroll
  for (int qf = 0; qf < 2; ++qf)
    qfr[qf] = *reinterpret_cast<const bf16x8*>(Qp + (size_t)(qw0 + qf * 16 + c15) * D_ + g * 8);

  f32x4 acc[2][2];
  const f32x4 zero4 = {0.f, 0.f, 0.f, 0.f};
#pragma unroll
  for (int qf = 0; qf < 2; ++qf)
#pragma unroll
    for (int dvf = 0; dvf < 2; ++dvf) acc[qf][dvf] = zero4;
  float lsum[2][4] = {};

  const uint32_t* mrow = mb + (size_t)b * Q_ * (N_ / 32);

  const int krow = t >> 2, kch = t & 3;
  const uint16_t* ksrc = Kh + ((size_t)(b * H_ + h) * N_ + nbase + krow) * 32 + kch * 8;
  const int vrow = t >> 4, vch = t & 15;
  const uint16_t* vsrc = Vh + ((size_t)(b * H_ + h) * 32 + vrow) * N_ + nbase + vch * 8;

  uint4 kreg = *(const uint4*)ksrc;
  uint4 vreg = *(const uint4*)vsrc;

  int cur = 0;
  for (int ss = 0; ss < SS; ++ss) {
    *(uint4*)&kst[cur][krow][kch * 8] = kreg;
    *(uint4*)&vst[cur][vrow][vch * 8] = vreg;
    if (ss < SS - 1) {
      kreg = *(const uint4*)(ksrc + (size_t)(ss + 1) * 128 * 32);
      vreg = *(const uint4*)(vsrc + (ss + 1) * 128);
    }
    lgkm0_barrier();

    const int nstart = nbase + ss * 128;
#pragma unroll
    for (int half = 0; half < 2; ++half) {
      uint32_t mw[2][4][2];
#pragma unroll
      for (int qf = 0; qf < 2; ++qf)
#pragma unroll
        for (int j = 0; j < 4; ++j) {
          const int q = qw0 + qf * 16 + 4 * g + j;
          const uint2 u = *reinterpret_cast<const uint2*>(
              &mrow[(size_t)q * (N_ / 32) + (nstart >> 5) + half * 2]);
          mw[qf][j][0] = u.x;
          mw[qf][j][1] = u.y;
        }
#pragma unroll
      for (int s2 = 0; s2 < 2; ++s2) {
        const int sub = half * 2 + s2;
        const int nl0 = sub * 32;
        bf16x8 kfr[2];
#pragma unroll
        for (int nf = 0; nf < 2; ++nf)
          kfr[nf] = *reinterpret_cast<const bf16x8*>(&kst[cur][nl0 + nf * 16 + c15][g * 8]);
        f32x4 s[2][2];
#pragma unroll
        for (int qf = 0; qf < 2; ++qf)
#pragma unroll
          for (int nf = 0; nf < 2; ++nf)
            s[qf][nf] = __builtin_amdgcn_mfma_f32_16x16x32_bf16(qfr[qf], kfr[nf], zero4, 0, 0, 0);

#pragma unroll
        for (int qf = 0; qf < 2; ++qf) {
#pragma unroll
          for (int j = 0; j < 4; ++j) {
            const uint32_t wmask = mw[qf][j][s2];
#pragma unroll
            for (int nf = 0; nf < 2; ++nf) {
              const int bit = nf * 16 + c15;
              const float p = ((wmask >> bit) & 1u) ? 0.0f : exp2f(s[qf][nf][j]);
              lsum[qf][j] += p;
              plds[wid][qf * 16 + 4 * g + j][nf * 16 + c15] = bfbits(p);
            }
          }
        }
        __asm__ volatile("s_waitcnt lgkmcnt(0)" ::: "memory");
#pragma unroll
        for (int qf = 0; qf < 2; ++qf) {
          const bf16x8 pa = *reinterpret_cast<const bf16x8*>(&plds[wid][qf * 16 + c15][g * 8]);
#pragma unroll
          for (int dvf = 0; dvf < 2; ++dvf) {
            const bf16x8 vb =
                *reinterpret_cast<const bf16x8*>(&vst[cur][dvf * 16 + c15][nl0 + g * 8]);
            acc[qf][dvf] = __builtin_amdgcn_mfma_f32_16x16x32_bf16(pa, vb, acc[qf][dvf], 0, 0, 0);
          }
        }
      }
    }
    __builtin_amdgcn_sched_barrier(0);
    cur ^= 1;
  }

#pragma unroll
  for (int qf = 0; qf < 2; ++qf)
#pragma unroll
    for (int j = 0; j < 4; ++j) {
      float v = lsum[qf][j];
      v += __shfl_xor(v, 1, 64);
      v += __shfl_xor(v, 2, 64);
      v += __shfl_xor(v, 4, 64);
      v += __shfl_xor(v, 8, 64);
      lsum[qf][j] = v;
    }

  uint16_t* cp = ctx_part + ((size_t)(b * H_ + h) * NC_ + nc) * Q_ * D_;
#pragma unroll
  for (int qf = 0; qf < 2; ++qf)
#pragma unroll
    for (int dvf = 0; dvf < 2; ++dvf)
#pragma unroll
      for (int j = 0; j < 4; ++j) {
        const int q = qw0 + qf * 16 + 4 * g + j;
        cp[(size_t)q * D_ + dvf * 16 + c15] = bfbits(acc[qf][dvf][j]);
      }
  if (c15 == 0) {
    float* lp = lsum_part + ((size_t)(b * H_ + h) * NC_ + nc) * Q_;
#pragma unroll
    for (int qf = 0; qf < 2; ++qf)
#pragma unroll
      for (int j = 0; j < 4; ++j) lp[qw0 + qf * 16 + 4 * g + j] = lsum[qf][j];
  }
}

// ---------------------------------------------------------------------------
// Kernel 4: combine partials (bf16) + out_proj (woT) + residual + LayerNorm.
// ---------------------------------------------------------------------------
__global__ __launch_bounds__(256) void epilogue(const uint16_t* __restrict__ ctx_part,
                                                const float* __restrict__ lsum_part,
                                                const float* __restrict__ queries,
                                                const float* __restrict__ woT,
                                                const float* __restrict__ bo,
                                                const float* __restrict__ gamma,
                                                const float* __restrict__ beta,
                                                float* __restrict__ out) {
  const int bq = blockIdx.x;
  const int b = bq >> 8, q = bq & 255;
  const int t = threadIdx.x;
  const int h = t >> 5, dv = t & 31;
  float cs = 0.f, ls = 0.f;
#pragma unroll 8
  for (int k = 0; k < NC_; ++k) {
    cs += bf2f(ctx_part[(((size_t)(b * H_ + h) * NC_ + k) * Q_ + q) * D_ + dv]);
    ls += lsum_part[((size_t)(b * H_ + h) * NC_ + k) * Q_ + q];
  }
  __shared__ float ctxrow[C_];
  ctxrow[t] = cs / ls;
  __syncthreads();
  float acc = bo[t];
#pragma unroll 8
  for (int j = 0; j < C_; ++j) acc = fmaf(ctxrow[j], woT[(size_t)j * C_ + t], acc);
  const float x = queries[(size_t)bq * C_ + t] + acc;
  float s1 = x, s2 = x * x;
  for (int o = 32; o > 0; o >>= 1) {
    s1 += __shfl_down(s1, o, 64);
    s2 += __shfl_down(s2, o, 64);
  }
  __shared__ float r1[4], r2[4];
  if ((t & 63) == 0) { r1[t >> 6] = s1; r2[t >> 6] = s2; }
  __syncthreads();
  const float mu = (r1[0] + r1[1] + r1[2] + r1[3]) * (1.0f / C_);
  const float e2 = (r2[0] + r2[1] + r2[2] + r2[3]) * (1.0f / C_);
  const float var = e2 - mu * mu;
  out[(size_t)bq * C_ + t] = (x - mu) * rsqrtf(var + 1e-5f) * gamma[t] + beta[t];
}

extern "C" void kernel_launch(void* const* d_in, const int* in_sizes, int n_in,
                              void* d_out, int out_size, void* d_ws, size_t ws_size,
                              hipStream_t stream) {
  const float* queries    = (const float*)d_in[0];
  const float* vidfeat    = (const float*)d_in[1];
  const float* vidmask    = (const float*)d_in[2];
  const float* posembed   = (const float*)d_in[3];
  const float* queryembed = (const float*)d_in[4];
  const float* inw        = (const float*)d_in[5];
  const float* inb        = (const float*)d_in[6];
  const float* outw       = (const float*)d_in[7];
  const float* outb       = (const float*)d_in[8];
  const float* gamma      = (const float*)d_in[9];
  const float* beta       = (const float*)d_in[10];
  float* out = (float*)d_out;

  char* ws = (char*)d_ws;
  size_t off = 0;
  uint16_t* Qb   = (uint16_t*)(ws + off); off += (size_t)B_ * H_ * Q_ * D_ * 2;      // 256 KB
  uint16_t* Kh   = (uint16_t*)(ws + off); off += (size_t)B_ * H_ * N_ * D_ * 2;      // 16.78 MB
  uint16_t* Vh   = (uint16_t*)(ws + off); off += (size_t)B_ * H_ * D_ * N_ * 2;      // 16.78 MB
  uint32_t* mb   = (uint32_t*)(ws + off); off += (size_t)B_ * Q_ * (N_ / 32) * 4;    // 1 MB
  uint16_t* wkv  = (uint16_t*)(ws + off); off += (size_t)768 * C_ * 2;               // 384 KB
  float* woT     = (float*)(ws + off);    off += (size_t)C_ * C_ * 4;                // 256 KB
  uint16_t* ctxp = (uint16_t*)(ws + off); off += (size_t)B_ * H_ * NC_ * Q_ * D_ * 2;// 8.39 MB
  float* lsump   = (float*)(ws + off);    off += (size_t)B_ * H_ * NC_ * Q_ * 4;     // 1 MB

  prep<<<dim3(160), dim3(256), 0, stream>>>(inw, outw, wkv, woT);
  kvqproj<<<dim3(1032), dim3(512), 0, stream>>>(vidfeat, posembed, queries, queryembed,
                                                wkv, vidmask, inb, Kh, Vh, Qb, mb);
  attn<<<dim3(B_ * H_ * NC_), dim3(512), 0, stream>>>(Qb, Kh, Vh, mb, ctxp, lsump);
  epilogue<<<dim3(B_ * Q_), dim3(256), 0, stream>>>(ctxp, lsump, queries, woT, outb,
                                                    gamma, beta, out);
}

// Round 16
// 100.675 us; speedup vs baseline: 1.2054x; 1.2054x over previous
//
#include <hip/hip_runtime.h>
#include <stdint.h>

// CrossAttentionLayer: B=2, Q=256, N=16384, C=256, H=8, d=32
#define B_ 2
#define Q_ 256
#define N_ 16384
#define C_ 256
#define H_ 8
#define D_ 32
#define NC_ 32                       // attention split-N chunks (512 keys/block)
#define SCALEQ 0.2550542176432015f   // (1/sqrt(32)) * log2(e)  [exp -> exp2]

typedef __bf16 bf16x8 __attribute__((ext_vector_type(8)));
typedef float f32x4 __attribute__((ext_vector_type(4)));

__device__ __forceinline__ uint16_t bfbits(float f) {
  union { __bf16 h; uint16_t u; } c; c.h = (__bf16)f; return c.u;
}
__device__ __forceinline__ float bf2f(uint16_t u) {
  union { uint32_t u; float f; } c; c.u = (uint32_t)u << 16;
  return c.f;
}
__device__ __forceinline__ uint32_t pk2(float a, float b) {
  union { struct { uint16_t lo, hi; } s; uint32_t u; } c;
  c.s.lo = bfbits(a); c.s.hi = bfbits(b);
  return c.u;  // fuses to v_cvt_pk_bf16_f32
}
__device__ __forceinline__ void lgkm0_barrier() {
  __builtin_amdgcn_sched_barrier(0);
  asm volatile("s_waitcnt lgkmcnt(0)" ::: "memory");
  __builtin_amdgcn_sched_barrier(0);
  __builtin_amdgcn_s_barrier();
  __builtin_amdgcn_sched_barrier(0);
}

// ---------------------------------------------------------------------------
// Kernel 1 "prep": blocks 0..95: in_proj_w (768x256) -> bf16; 96..159:
// woT = out_proj_w^T; 160..671: pack vid_mask -> bitmask (bit=1 => blocked)
// with all-blocked fallback.
// ---------------------------------------------------------------------------
__global__ __launch_bounds__(256) void prep(const float* __restrict__ inw,
                                            const float* __restrict__ outw,
                                            const float* __restrict__ vm,
                                            uint16_t* __restrict__ wb,
                                            float* __restrict__ woT,
                                            uint32_t* __restrict__ mb) {
  __shared__ __align__(16) char sh[4352];
  const int bid = blockIdx.x;
  const int t = threadIdx.x;
  if (bid < 96) {
    const int i = (bid * 256 + t) * 8;
    const float4 a = *reinterpret_cast<const float4*>(inw + i);
    const float4 b = *reinterpret_cast<const float4*>(inw + i + 4);
    ushort4 lo = {bfbits(a.x), bfbits(a.y), bfbits(a.z), bfbits(a.w)};
    ushort4 hi = {bfbits(b.x), bfbits(b.y), bfbits(b.z), bfbits(b.w)};
    *reinterpret_cast<ushort4*>(wb + i) = lo;
    *reinterpret_cast<ushort4*>(wb + i + 4) = hi;
  } else if (bid < 160) {
    float(*s)[33] = reinterpret_cast<float(*)[33]>(sh);
    const int bb = bid - 96;
    const int bx = bb & 7, by = bb >> 3;
    const int r0 = by * 32, c0 = bx * 32;
    const int tr = t >> 5, tc = t & 31;
#pragma unroll
    for (int k = 0; k < 4; ++k)
      s[tr + 8 * k][tc] = outw[(size_t)(r0 + tr + 8 * k) * 256 + c0 + tc];
    __syncthreads();
#pragma unroll
    for (int k = 0; k < 4; ++k)
      woT[(size_t)(c0 + tr + 8 * k) * 256 + r0 + tc] = s[tc][tr + 8 * k];
  } else {
    uint8_t(*nib)[256] = reinterpret_cast<uint8_t(*)[256]>(sh);
    __shared__ int wcnt[4];
    __shared__ int tot;
    const int bq = bid - 160;
    const float* row = vm + (size_t)bq * N_;
    const int lane = t & 63;
    int cnt = 0;
#pragma unroll
    for (int i = 0; i < 16; ++i) {
      const float4 v = *reinterpret_cast<const float4*>(&row[i * 1024 + 4 * t]);
      const uint32_t nb = (v.x < 0.5f ? 1u : 0u) | (v.y < 0.5f ? 2u : 0u) |
                          (v.z < 0.5f ? 4u : 0u) | (v.w < 0.5f ? 8u : 0u);
      nib[i][t] = (uint8_t)nb;
      cnt += __popc(nb);
    }
    for (int o = 32; o > 0; o >>= 1) cnt += __shfl_down(cnt, o, 64);
    if (lane == 0) wcnt[t >> 6] = cnt;
    __syncthreads();
    if (t == 0) tot = wcnt[0] + wcnt[1] + wcnt[2] + wcnt[3];
    __syncthreads();
    const bool allb = (tot == N_);
    uint32_t* dst = mb + (size_t)bq * 512;
#pragma unroll
    for (int k = 0; k < 2; ++k) {
      const int w = k * 256 + t;
      const int i = w >> 5, tw = w & 31;
      const uint2 u = *reinterpret_cast<const uint2*>(&nib[i][8 * tw]);
      uint32_t y0 = u.x & 0x0F0F0F0Fu; y0 = y0 | (y0 >> 4);
      uint32_t y1 = u.y & 0x0F0F0F0Fu; y1 = y1 | (y1 >> 4);
      const uint32_t word = (y0 & 0xFFu) | (((y0 >> 16) & 0xFFu) << 8) |
                            ((y1 & 0xFFu) << 16) | (((y1 >> 16) & 0xFFu) << 24);
      dst[w] = allb ? 0u : word;
    }
  }
}

// ---------------------------------------------------------------------------
// Kernel 2 "kvqproj" (R14 structure, no interleave): FUSED K+V per block.
// Blocks 0..7: Q projection via MFMA. Blocks 8..519: KV blocks, n-tile = 64.
// Wave w computes BOTH K-head-w and V-head-w; acc 64 VGPR; single bf16
// weight set per step from wkv; 2-deep act prefetch; XOR-swizzled LDS;
// lgkm-only barrier. Outputs: Kh [b][h][n][32], Vh [b][h][32][n].
// Qb pre-scaled by SCALEQ (log2e folded -> attn uses exp2).
// ---------------------------------------------------------------------------
__global__ __launch_bounds__(512, 2) void kvqproj(const float* __restrict__ vf,
                                                  const float* __restrict__ pe,
                                                  const float* __restrict__ queries,
                                                  const float* __restrict__ qembed,
                                                  const uint16_t* __restrict__ wkv,
                                                  const float* __restrict__ bias,
                                                  uint16_t* __restrict__ Kh,
                                                  uint16_t* __restrict__ Vh,
                                                  uint16_t* __restrict__ Qb) {
  __shared__ __align__(16) uint16_t shpool[8][64][40];  // KV path uses [0..3]
  const int bid = blockIdx.x;
  const int t = threadIdx.x, wid = t >> 6, lane = t & 63;
  const int g = lane >> 4, c15 = lane & 15;

  if (bid >= 8) {
    const int kb = bid - 8;
    const int b = kb >> 8, nt = kb & 255;
    const int n0 = nt * 64;
    const int w = wid;  // head

    const uint16_t* WsecK = wkv + (size_t)(256 + w * 32 + c15) * C_;
    const uint16_t* WsecV = wkv + (size_t)(512 + w * 32 + c15) * C_;

    f32x4 acck[8];  // [cf*4+nf]: D[row=cout][col=n]
    f32x4 accv[8];  // [nf*2+cf]: D[row=n][col=cout]
#pragma unroll
    for (int cf = 0; cf < 2; ++cf) {
      f32x4 ivk;
#pragma unroll
      for (int j = 0; j < 4; ++j) ivk[j] = bias[256 + w * 32 + cf * 16 + 4 * g + j];
      const float bv = bias[512 + w * 32 + cf * 16 + c15];
      const f32x4 ivv = {bv, bv, bv, bv};
#pragma unroll
      for (int nf = 0; nf < 4; ++nf) {
        acck[cf * 4 + nf] = ivk;
        accv[nf * 2 + cf] = ivv;
      }
    }

    const int cq = t >> 5, q2 = t & 31;
    const float* Xb = vf + ((size_t)b * C_ + 2 * cq) * N_ + n0 + 2 * q2;
    const float* Pb = pe + ((size_t)b * C_ + 2 * cq) * N_ + n0 + 2 * q2;
    const int cqs = cq ^ (((q2 >> 2) & 3) << 2);  // 16B-block XOR swizzle

    float2 xA0, xA1, pA0, pA1, xB0, xB1, pB0, pB1;
    bf16x8 Wk[2], Wv[2];

#define LOADW(s)                                                             \
    {                                                                        \
      _Pragma("unroll") for (int cf = 0; cf < 2; ++cf) {                     \
        Wk[cf] = *(const bf16x8*)(WsecK + (size_t)cf * 16 * C_ + (s) * 32 + g * 8); \
        Wv[cf] = *(const bf16x8*)(WsecV + (size_t)cf * 16 * C_ + (s) * 32 + g * 8); \
      }                                                                      \
    }
#define LOADA(X0, X1, P0, P1, s)                                             \
    {                                                                        \
      const float* x_ = Xb + (size_t)(s) * 32 * N_;                          \
      const float* p_ = Pb + (size_t)(s) * 32 * N_;                          \
      X0 = *(const float2*)x_;                                               \
      X1 = *(const float2*)(x_ + N_);                                        \
      P0 = *(const float2*)p_;                                               \
      P1 = *(const float2*)(p_ + N_);                                        \
    }
#define WRITEA(X0, X1, P0, P1, bufp)                                         \
    {                                                                        \
      *(uint32_t*)&shpool[bufp][2 * q2][2 * cqs]     = pk2(X0.x + P0.x, X1.x + P1.x); \
      *(uint32_t*)&shpool[bufp][2 * q2 + 1][2 * cqs] = pk2(X0.y + P0.y, X1.y + P1.y); \
      *(uint32_t*)&shpool[(bufp) + 1][2 * q2][2 * cqs]     = pk2(X0.x, X1.x); \
      *(uint32_t*)&shpool[(bufp) + 1][2 * q2 + 1][2 * cqs] = pk2(X0.y, X1.y); \
    }
#define COMPUTE(bufp)                                                        \
    {                                                                        \
      _Pragma("unroll") for (int nf = 0; nf < 4; ++nf) {                     \
        const int r_ = nf * 16 + c15;                                        \
        const int o_ = (g ^ ((r_ >> 3) & 3)) * 8;                            \
        const bf16x8 Fp = *(const bf16x8*)&shpool[bufp][r_][o_];             \
        const bf16x8 Fv = *(const bf16x8*)&shpool[(bufp) + 1][r_][o_];       \
        _Pragma("unroll") for (int cf = 0; cf < 2; ++cf) {                   \
          acck[cf * 4 + nf] = __builtin_amdgcn_mfma_f32_16x16x32_bf16(       \
              Wk[cf], Fp, acck[cf * 4 + nf], 0, 0, 0);                       \
          accv[nf * 2 + cf] = __builtin_amdgcn_mfma_f32_16x16x32_bf16(       \
              Fv, Wv[cf], accv[nf * 2 + cf], 0, 0, 0);                       \
        }                                                                    \
      }                                                                      \
    }

    // prologue: acts(0) -> A, acts(1) -> B
    LOADA(xA0, xA1, pA0, pA1, 0);
    LOADA(xB0, xB1, pB0, pB1, 1);
    // s=0
    LOADW(0); WRITEA(xA0, xA1, pA0, pA1, 0); LOADA(xA0, xA1, pA0, pA1, 2);
    lgkm0_barrier(); COMPUTE(0); __builtin_amdgcn_sched_barrier(0);
    // s=1
    LOADW(1); WRITEA(xB0, xB1, pB0, pB1, 2); LOADA(xB0, xB1, pB0, pB1, 3);
    lgkm0_barrier(); COMPUTE(2); __builtin_amdgcn_sched_barrier(0);
    // s=2
    LOADW(2); WRITEA(xA0, xA1, pA0, pA1, 0); LOADA(xA0, xA1, pA0, pA1, 4);
    lgkm0_barrier(); COMPUTE(0); __builtin_amdgcn_sched_barrier(0);
    // s=3
    LOADW(3); WRITEA(xB0, xB1, pB0, pB1, 2); LOADA(xB0, xB1, pB0, pB1, 5);
    lgkm0_barrier(); COMPUTE(2); __builtin_amdgcn_sched_barrier(0);
    // s=4
    LOADW(4); WRITEA(xA0, xA1, pA0, pA1, 0); LOADA(xA0, xA1, pA0, pA1, 6);
    lgkm0_barrier(); COMPUTE(0); __builtin_amdgcn_sched_barrier(0);
    // s=5
    LOADW(5); WRITEA(xB0, xB1, pB0, pB1, 2); LOADA(xB0, xB1, pB0, pB1, 7);
    lgkm0_barrier(); COMPUTE(2); __builtin_amdgcn_sched_barrier(0);
    // s=6
    LOADW(6); WRITEA(xA0, xA1, pA0, pA1, 0);
    lgkm0_barrier(); COMPUTE(0); __builtin_amdgcn_sched_barrier(0);
    // s=7
    LOADW(7); WRITEA(xB0, xB1, pB0, pB1, 2);
    lgkm0_barrier(); COMPUTE(2); __builtin_amdgcn_sched_barrier(0);

#undef LOADW
#undef LOADA
#undef WRITEA
#undef COMPUTE

    // K store: lane holds 4 consecutive dk at n = n0 + nf*16 + c15
    uint16_t* Kp = Kh + (size_t)(b * H_ + w) * N_ * D_;
#pragma unroll
    for (int cf = 0; cf < 2; ++cf)
#pragma unroll
      for (int nf = 0; nf < 4; ++nf) {
        const f32x4 a = acck[cf * 4 + nf];
        uint2 pkv;
        pkv.x = pk2(a[0], a[1]);
        pkv.y = pk2(a[2], a[3]);
        *(uint2*)&Kp[(size_t)(n0 + nf * 16 + c15) * D_ + cf * 16 + 4 * g] = pkv;
      }
    // V store: lane holds 4 consecutive n at dv = cf*16 + c15
    uint16_t* Vp = Vh + (size_t)(b * H_ + w) * D_ * N_;
#pragma unroll
    for (int nf = 0; nf < 4; ++nf)
#pragma unroll
      for (int cf = 0; cf < 2; ++cf) {
        const f32x4 a = accv[nf * 2 + cf];
        uint2 pkv;
        pkv.x = pk2(a[0], a[1]);
        pkv.y = pk2(a[2], a[3]);
        *(uint2*)&Vp[(size_t)(cf * 16 + c15) * N_ + n0 + nf * 16 + 4 * g] = pkv;
      }
  } else {
    // ---- Q projection: 8 blocks x 64 q-rows ----
    const int qb = bid;
    const int q0g = qb * 64;
    const int b = q0g >> 8, q0 = q0g & 255;
    const int r = t >> 3, c0 = (t & 7) * 32, s = t & 7;
    const float* Qrow = queries + (size_t)(q0g + r) * C_ + c0;
    const float* Erow = qembed + (size_t)(q0g + r) * C_ + c0;
#pragma unroll
    for (int ph = 0; ph < 2; ++ph) {
      float4 a4[4], e4[4];
#pragma unroll
      for (int k = 0; k < 4; ++k) a4[k] = reinterpret_cast<const float4*>(Qrow + ph * 16)[k];
#pragma unroll
      for (int k = 0; k < 4; ++k) e4[k] = reinterpret_cast<const float4*>(Erow + ph * 16)[k];
      const float* af = reinterpret_cast<const float*>(a4);
      const float* ef = reinterpret_cast<const float*>(e4);
#pragma unroll
      for (int i = 0; i < 16; ++i) {
        const int cl = ph * 16 + i;
        const int col = cl ^ (8 * ((r >> 3) & 3));
        shpool[s][r][col] = bfbits(af[i] + ef[i]);
      }
      __builtin_amdgcn_sched_barrier(0);
    }
    lgkm0_barrier();

    const int w = wid;  // head = w
    f32x4 acc[4][2];
#pragma unroll
    for (int nf = 0; nf < 2; ++nf) {
      const float bv = bias[w * 32 + nf * 16 + c15];
      const f32x4 iv = {bv, bv, bv, bv};
#pragma unroll
      for (int qf = 0; qf < 4; ++qf) acc[qf][nf] = iv;
    }
#pragma unroll
    for (int s8 = 0; s8 < 8; ++s8) {
      bf16x8 Bf[2];
#pragma unroll
      for (int nf = 0; nf < 2; ++nf)
        Bf[nf] = *reinterpret_cast<const bf16x8*>(
            wkv + (size_t)(w * 32 + nf * 16 + c15) * C_ + s8 * 32 + g * 8);
#pragma unroll
      for (int qf = 0; qf < 4; ++qf) {
        const int rr = qf * 16 + c15;
        const bf16x8 Af = *reinterpret_cast<const bf16x8*>(
            &shpool[s8][rr][8 * (g ^ ((rr >> 3) & 3))]);
#pragma unroll
        for (int nf = 0; nf < 2; ++nf)
          acc[qf][nf] = __builtin_amdgcn_mfma_f32_16x16x32_bf16(Af, Bf[nf], acc[qf][nf], 0, 0, 0);
      }
    }
#pragma unroll
    for (int qf = 0; qf < 4; ++qf)
#pragma unroll
      for (int nf = 0; nf < 2; ++nf)
#pragma unroll
        for (int j = 0; j < 4; ++j) {
          const int q = q0 + qf * 16 + 4 * g + j;
          const int dk = nf * 16 + c15;
          Qb[((size_t)(b * H_ + w) * Q_ + q) * D_ + dk] = bfbits(acc[qf][nf][j] * SCALEQ);
        }
  }
}

// ---------------------------------------------------------------------------
// Kernel 3: attention over an N-chunk of 512 keys, all 256 queries of one
// (b,h). p = exp2(s) (log2e folded into Q scale). ctx partials bf16.
// ---------------------------------------------------------------------------
__global__ __launch_bounds__(512) void attn(const uint16_t* __restrict__ Qb,
                                            const uint16_t* __restrict__ Kh,
                                            const uint16_t* __restrict__ Vh,
                                            const uint32_t* __restrict__ mb,
                                            uint16_t* __restrict__ ctx_part,
                                            float* __restrict__ lsum_part) {
  const int bid = blockIdx.x;
  const int nc = bid & 31, h = (bid >> 5) & 7, b = bid >> 8;
  const int t = threadIdx.x, wid = t >> 6, lane = t & 63;
  const int g = lane >> 4, c15 = lane & 15;
  const int qw0 = wid * 32;
  const int nbase = nc * (N_ / NC_);
  constexpr int SS = (N_ / NC_) / 128;

  __shared__ __align__(16) uint16_t kst[2][128][40];
  __shared__ __align__(16) uint16_t vst[2][32][136];
  __shared__ __align__(16) uint16_t plds[8][32][40];

  const uint16_t* Qp = Qb + (size_t)(b * H_ + h) * Q_ * D_;
  bf16x8 qfr[2];
#pragma unroll
  for (int qf = 0; qf < 2; ++qf)
    qfr[qf] = *reinterpret_cast<const bf16x8*>(Qp + (size_t)(qw0 + qf * 16 + c15) * D_ + g * 8);

  f32x4 acc[2][2];
  const f32x4 zero4 = {0.f, 0.f, 0.f, 0.f};
#pragma unroll
  for (int qf = 0; qf < 2; ++qf)
#pragma unroll
    for (int dvf = 0; dvf < 2; ++dvf) acc[qf][dvf] = zero4;
  float lsum[2][4] = {};

  const uint32_t* mrow = mb + (size_t)b * Q_ * (N_ / 32);

  const int krow = t >> 2, kch = t & 3;
  const uint16_t* ksrc = Kh + ((size_t)(b * H_ + h) * N_ + nbase + krow) * 32 + kch * 8;
  const int vrow = t >> 4, vch = t & 15;
  const uint16_t* vsrc = Vh + ((size_t)(b * H_ + h) * 32 + vrow) * N_ + nbase + vch * 8;

  uint4 kreg = *(const uint4*)ksrc;
  uint4 vreg = *(const uint4*)vsrc;

  int cur = 0;
  for (int ss = 0; ss < SS; ++ss) {
    *(uint4*)&kst[cur][krow][kch * 8] = kreg;
    *(uint4*)&vst[cur][vrow][vch * 8] = vreg;
    if (ss < SS - 1) {
      kreg = *(const uint4*)(ksrc + (size_t)(ss + 1) * 128 * 32);
      vreg = *(const uint4*)(vsrc + (ss + 1) * 128);
    }
    lgkm0_barrier();

    const int nstart = nbase + ss * 128;
#pragma unroll
    for (int half = 0; half < 2; ++half) {
      uint32_t mw[2][4][2];
#pragma unroll
      for (int qf = 0; qf < 2; ++qf)
#pragma unroll
        for (int j = 0; j < 4; ++j) {
          const int q = qw0 + qf * 16 + 4 * g + j;
          const uint2 u = *reinterpret_cast<const uint2*>(
              &mrow[(size_t)q * (N_ / 32) + (nstart >> 5) + half * 2]);
          mw[qf][j][0] = u.x;
          mw[qf][j][1] = u.y;
        }
#pragma unroll
      for (int s2 = 0; s2 < 2; ++s2) {
        const int sub = half * 2 + s2;
        const int nl0 = sub * 32;
        bf16x8 kfr[2];
#pragma unroll
        for (int nf = 0; nf < 2; ++nf)
          kfr[nf] = *reinterpret_cast<const bf16x8*>(&kst[cur][nl0 + nf * 16 + c15][g * 8]);
        f32x4 s[2][2];
#pragma unroll
        for (int qf = 0; qf < 2; ++qf)
#pragma unroll
          for (int nf = 0; nf < 2; ++nf)
            s[qf][nf] = __builtin_amdgcn_mfma_f32_16x16x32_bf16(qfr[qf], kfr[nf], zero4, 0, 0, 0);

#pragma unroll
        for (int qf = 0; qf < 2; ++qf) {
#pragma unroll
          for (int j = 0; j < 4; ++j) {
            const uint32_t wmask = mw[qf][j][s2];
#pragma unroll
            for (int nf = 0; nf < 2; ++nf) {
              const int bit = nf * 16 + c15;
              const float p = ((wmask >> bit) & 1u) ? 0.0f : exp2f(s[qf][nf][j]);
              lsum[qf][j] += p;
              plds[wid][qf * 16 + 4 * g + j][nf * 16 + c15] = bfbits(p);
            }
          }
        }
        __asm__ volatile("s_waitcnt lgkmcnt(0)" ::: "memory");
#pragma unroll
        for (int qf = 0; qf < 2; ++qf) {
          const bf16x8 pa = *reinterpret_cast<const bf16x8*>(&plds[wid][qf * 16 + c15][g * 8]);
#pragma unroll
          for (int dvf = 0; dvf < 2; ++dvf) {
            const bf16x8 vb =
                *reinterpret_cast<const bf16x8*>(&vst[cur][dvf * 16 + c15][nl0 + g * 8]);
            acc[qf][dvf] = __builtin_amdgcn_mfma_f32_16x16x32_bf16(pa, vb, acc[qf][dvf], 0, 0, 0);
          }
        }
      }
    }
    __builtin_amdgcn_sched_barrier(0);
    cur ^= 1;
  }

#pragma unroll
  for (int qf = 0; qf < 2; ++qf)
#pragma unroll
    for (int j = 0; j < 4; ++j) {
      float v = lsum[qf][j];
      v += __shfl_xor(v, 1, 64);
      v += __shfl_xor(v, 2, 64);
      v += __shfl_xor(v, 4, 64);
      v += __shfl_xor(v, 8, 64);
      lsum[qf][j] = v;
    }

  uint16_t* cp = ctx_part + ((size_t)(b * H_ + h) * NC_ + nc) * Q_ * D_;
#pragma unroll
  for (int qf = 0; qf < 2; ++qf)
#pragma unroll
    for (int dvf = 0; dvf < 2; ++dvf)
#pragma unroll
      for (int j = 0; j < 4; ++j) {
        const int q = qw0 + qf * 16 + 4 * g + j;
        cp[(size_t)q * D_ + dvf * 16 + c15] = bfbits(acc[qf][dvf][j]);
      }
  if (c15 == 0) {
    float* lp = lsum_part + ((size_t)(b * H_ + h) * NC_ + nc) * Q_;
#pragma unroll
    for (int qf = 0; qf < 2; ++qf)
#pragma unroll
      for (int j = 0; j < 4; ++j) lp[qw0 + qf * 16 + 4 * g + j] = lsum[qf][j];
  }
}

// ---------------------------------------------------------------------------
// Kernel 4: combine partials (bf16) + out_proj (woT) + residual + LayerNorm.
// ---------------------------------------------------------------------------
__global__ __launch_bounds__(256) void epilogue(const uint16_t* __restrict__ ctx_part,
                                                const float* __restrict__ lsum_part,
                                                const float* __restrict__ queries,
                                                const float* __restrict__ woT,
                                                const float* __restrict__ bo,
                                                const float* __restrict__ gamma,
                                                const float* __restrict__ beta,
                                                float* __restrict__ out) {
  const int bq = blockIdx.x;
  const int b = bq >> 8, q = bq & 255;
  const int t = threadIdx.x;
  const int h = t >> 5, dv = t & 31;
  float cs = 0.f, ls = 0.f;
#pragma unroll 8
  for (int k = 0; k < NC_; ++k) {
    cs += bf2f(ctx_part[(((size_t)(b * H_ + h) * NC_ + k) * Q_ + q) * D_ + dv]);
    ls += lsum_part[((size_t)(b * H_ + h) * NC_ + k) * Q_ + q];
  }
  __shared__ float ctxrow[C_];
  ctxrow[t] = cs / ls;
  __syncthreads();
  float acc = bo[t];
#pragma unroll 8
  for (int j = 0; j < C_; ++j) acc = fmaf(ctxrow[j], woT[(size_t)j * C_ + t], acc);
  const float x = queries[(size_t)bq * C_ + t] + acc;
  float s1 = x, s2 = x * x;
  for (int o = 32; o > 0; o >>= 1) {
    s1 += __shfl_down(s1, o, 64);
    s2 += __shfl_down(s2, o, 64);
  }
  __shared__ float r1[4], r2[4];
  if ((t & 63) == 0) { r1[t >> 6] = s1; r2[t >> 6] = s2; }
  __syncthreads();
  const float mu = (r1[0] + r1[1] + r1[2] + r1[3]) * (1.0f / C_);
  const float e2 = (r2[0] + r2[1] + r2[2] + r2[3]) * (1.0f / C_);
  const float var = e2 - mu * mu;
  out[(size_t)bq * C_ + t] = (x - mu) * rsqrtf(var + 1e-5f) * gamma[t] + beta[t];
}

extern "C" void kernel_launch(void* const* d_in, const int* in_sizes, int n_in,
                              void* d_out, int out_size, void* d_ws, size_t ws_size,
                              hipStream_t stream) {
  const float* queries    = (const float*)d_in[0];
  const float* vidfeat    = (const float*)d_in[1];
  const float* vidmask    = (const float*)d_in[2];
  const float* posembed   = (const float*)d_in[3];
  const float* queryembed = (const float*)d_in[4];
  const float* inw        = (const float*)d_in[5];
  const float* inb        = (const float*)d_in[6];
  const float* outw       = (const float*)d_in[7];
  const float* outb       = (const float*)d_in[8];
  const float* gamma      = (const float*)d_in[9];
  const float* beta       = (const float*)d_in[10];
  float* out = (float*)d_out;

  char* ws = (char*)d_ws;
  size_t off = 0;
  uint16_t* Qb   = (uint16_t*)(ws + off); off += (size_t)B_ * H_ * Q_ * D_ * 2;      // 256 KB
  uint16_t* Kh   = (uint16_t*)(ws + off); off += (size_t)B_ * H_ * N_ * D_ * 2;      // 16.78 MB
  uint16_t* Vh   = (uint16_t*)(ws + off); off += (size_t)B_ * H_ * D_ * N_ * 2;      // 16.78 MB
  uint32_t* mb   = (uint32_t*)(ws + off); off += (size_t)B_ * Q_ * (N_ / 32) * 4;    // 1 MB
  uint16_t* wkv  = (uint16_t*)(ws + off); off += (size_t)768 * C_ * 2;               // 384 KB
  float* woT     = (float*)(ws + off);    off += (size_t)C_ * C_ * 4;                // 256 KB
  uint16_t* ctxp = (uint16_t*)(ws + off); off += (size_t)B_ * H_ * NC_ * Q_ * D_ * 2;// 8.39 MB
  float* lsump   = (float*)(ws + off);    off += (size_t)B_ * H_ * NC_ * Q_ * 4;     // 1 MB

  prep<<<dim3(672), dim3(256), 0, stream>>>(inw, outw, vidmask, wkv, woT, mb);
  kvqproj<<<dim3(520), dim3(512), 0, stream>>>(vidfeat, posembed, queries, queryembed,
                                               wkv, inb, Kh, Vh, Qb);
  attn<<<dim3(B_ * H_ * NC_), dim3(512), 0, stream>>>(Qb, Kh, Vh, mb, ctxp, lsump);
  epilogue<<<dim3(B_ * Q_), dim3(256), 0, stream>>>(ctxp, lsump, queries, woT, outb,
                                                    gamma, beta, out);
}

// Round 17
// 94.675 us; speedup vs baseline: 1.2818x; 1.0634x over previous
//
#include <hip/hip_runtime.h>
#include <stdint.h>

// CrossAttentionLayer: B=2, Q=256, N=16384, C=256, H=8, d=32
#define B_ 2
#define Q_ 256
#define N_ 16384
#define C_ 256
#define H_ 8
#define D_ 32
#define NC_ 32                       // attention split-N chunks (512 keys/block)
#define SCALEQ 0.2550542176432015f   // (1/sqrt(32)) * log2(e)  [exp -> exp2]

typedef __bf16 bf16x8 __attribute__((ext_vector_type(8)));
typedef float f32x4 __attribute__((ext_vector_type(4)));

__device__ __forceinline__ uint16_t bfbits(float f) {
  union { __bf16 h; uint16_t u; } c; c.h = (__bf16)f; return c.u;
}
__device__ __forceinline__ float bf2f(uint16_t u) {
  union { uint32_t u; float f; } c; c.u = (uint32_t)u << 16;
  return c.f;
}
__device__ __forceinline__ uint32_t pk2(float a, float b) {
  union { struct { uint16_t lo, hi; } s; uint32_t u; } c;
  c.s.lo = bfbits(a); c.s.hi = bfbits(b);
  return c.u;  // fuses to v_cvt_pk_bf16_f32
}
__device__ __forceinline__ void lgkm0_barrier() {
  __builtin_amdgcn_sched_barrier(0);
  asm volatile("s_waitcnt lgkmcnt(0)" ::: "memory");
  __builtin_amdgcn_sched_barrier(0);
  __builtin_amdgcn_s_barrier();
  __builtin_amdgcn_sched_barrier(0);
}

// ---------------------------------------------------------------------------
// Kernel 1 "prep": blocks 0..95: in_proj_w (768x256) -> bf16; 96..159:
// woT = out_proj_w^T; 160..671: pack vid_mask -> bitmask (bit=1 => blocked)
// with all-blocked fallback.
// ---------------------------------------------------------------------------
__global__ __launch_bounds__(256) void prep(const float* __restrict__ inw,
                                            const float* __restrict__ outw,
                                            const float* __restrict__ vm,
                                            uint16_t* __restrict__ wb,
                                            float* __restrict__ woT,
                                            uint32_t* __restrict__ mb) {
  __shared__ __align__(16) char sh[4352];
  const int bid = blockIdx.x;
  const int t = threadIdx.x;
  if (bid < 96) {
    const int i = (bid * 256 + t) * 8;
    const float4 a = *reinterpret_cast<const float4*>(inw + i);
    const float4 b = *reinterpret_cast<const float4*>(inw + i + 4);
    ushort4 lo = {bfbits(a.x), bfbits(a.y), bfbits(a.z), bfbits(a.w)};
    ushort4 hi = {bfbits(b.x), bfbits(b.y), bfbits(b.z), bfbits(b.w)};
    *reinterpret_cast<ushort4*>(wb + i) = lo;
    *reinterpret_cast<ushort4*>(wb + i + 4) = hi;
  } else if (bid < 160) {
    float(*s)[33] = reinterpret_cast<float(*)[33]>(sh);
    const int bb = bid - 96;
    const int bx = bb & 7, by = bb >> 3;
    const int r0 = by * 32, c0 = bx * 32;
    const int tr = t >> 5, tc = t & 31;
#pragma unroll
    for (int k = 0; k < 4; ++k)
      s[tr + 8 * k][tc] = outw[(size_t)(r0 + tr + 8 * k) * 256 + c0 + tc];
    __syncthreads();
#pragma unroll
    for (int k = 0; k < 4; ++k)
      woT[(size_t)(c0 + tr + 8 * k) * 256 + r0 + tc] = s[tc][tr + 8 * k];
  } else {
    uint8_t(*nib)[256] = reinterpret_cast<uint8_t(*)[256]>(sh);
    __shared__ int wcnt[4];
    __shared__ int tot;
    const int bq = bid - 160;
    const float* row = vm + (size_t)bq * N_;
    const int lane = t & 63;
    int cnt = 0;
#pragma unroll
    for (int i = 0; i < 16; ++i) {
      const float4 v = *reinterpret_cast<const float4*>(&row[i * 1024 + 4 * t]);
      const uint32_t nb = (v.x < 0.5f ? 1u : 0u) | (v.y < 0.5f ? 2u : 0u) |
                          (v.z < 0.5f ? 4u : 0u) | (v.w < 0.5f ? 8u : 0u);
      nib[i][t] = (uint8_t)nb;
      cnt += __popc(nb);
    }
    for (int o = 32; o > 0; o >>= 1) cnt += __shfl_down(cnt, o, 64);
    if (lane == 0) wcnt[t >> 6] = cnt;
    __syncthreads();
    if (t == 0) tot = wcnt[0] + wcnt[1] + wcnt[2] + wcnt[3];
    __syncthreads();
    const bool allb = (tot == N_);
    uint32_t* dst = mb + (size_t)bq * 512;
#pragma unroll
    for (int k = 0; k < 2; ++k) {
      const int w = k * 256 + t;
      const int i = w >> 5, tw = w & 31;
      const uint2 u = *reinterpret_cast<const uint2*>(&nib[i][8 * tw]);
      uint32_t y0 = u.x & 0x0F0F0F0Fu; y0 = y0 | (y0 >> 4);
      uint32_t y1 = u.y & 0x0F0F0F0Fu; y1 = y1 | (y1 >> 4);
      const uint32_t word = (y0 & 0xFFu) | (((y0 >> 16) & 0xFFu) << 8) |
                            ((y1 & 0xFFu) << 16) | (((y1 >> 16) & 0xFFu) << 24);
      dst[w] = allb ? 0u : word;
    }
  }
}

// ---------------------------------------------------------------------------
// Kernel 2 "kvqproj" (verified base): FUSED K+V per block, no interleave.
// Blocks 0..7: Q projection via MFMA. Blocks 8..519: KV blocks, n-tile = 64.
// Outputs: Kh [b][h][n][32], Vh [b][h][32][n]. Qb pre-scaled by SCALEQ.
// ---------------------------------------------------------------------------
__global__ __launch_bounds__(512, 2) void kvqproj(const float* __restrict__ vf,
                                                  const float* __restrict__ pe,
                                                  const float* __restrict__ queries,
                                                  const float* __restrict__ qembed,
                                                  const uint16_t* __restrict__ wkv,
                                                  const float* __restrict__ bias,
                                                  uint16_t* __restrict__ Kh,
                                                  uint16_t* __restrict__ Vh,
                                                  uint16_t* __restrict__ Qb) {
  __shared__ __align__(16) uint16_t shpool[8][64][40];  // KV path uses [0..3]
  const int bid = blockIdx.x;
  const int t = threadIdx.x, wid = t >> 6, lane = t & 63;
  const int g = lane >> 4, c15 = lane & 15;

  if (bid >= 8) {
    const int kb = bid - 8;
    const int b = kb >> 8, nt = kb & 255;
    const int n0 = nt * 64;
    const int w = wid;  // head

    const uint16_t* WsecK = wkv + (size_t)(256 + w * 32 + c15) * C_;
    const uint16_t* WsecV = wkv + (size_t)(512 + w * 32 + c15) * C_;

    f32x4 acck[8];  // [cf*4+nf]: D[row=cout][col=n]
    f32x4 accv[8];  // [nf*2+cf]: D[row=n][col=cout]
#pragma unroll
    for (int cf = 0; cf < 2; ++cf) {
      f32x4 ivk;
#pragma unroll
      for (int j = 0; j < 4; ++j) ivk[j] = bias[256 + w * 32 + cf * 16 + 4 * g + j];
      const float bv = bias[512 + w * 32 + cf * 16 + c15];
      const f32x4 ivv = {bv, bv, bv, bv};
#pragma unroll
      for (int nf = 0; nf < 4; ++nf) {
        acck[cf * 4 + nf] = ivk;
        accv[nf * 2 + cf] = ivv;
      }
    }

    const int cq = t >> 5, q2 = t & 31;
    const float* Xb = vf + ((size_t)b * C_ + 2 * cq) * N_ + n0 + 2 * q2;
    const float* Pb = pe + ((size_t)b * C_ + 2 * cq) * N_ + n0 + 2 * q2;
    const int cqs = cq ^ (((q2 >> 2) & 3) << 2);  // 16B-block XOR swizzle

    float2 xA0, xA1, pA0, pA1, xB0, xB1, pB0, pB1;
    bf16x8 Wk[2], Wv[2];

#define LOADW(s)                                                             \
    {                                                                        \
      _Pragma("unroll") for (int cf = 0; cf < 2; ++cf) {                     \
        Wk[cf] = *(const bf16x8*)(WsecK + (size_t)cf * 16 * C_ + (s) * 32 + g * 8); \
        Wv[cf] = *(const bf16x8*)(WsecV + (size_t)cf * 16 * C_ + (s) * 32 + g * 8); \
      }                                                                      \
    }
#define LOADA(X0, X1, P0, P1, s)                                             \
    {                                                                        \
      const float* x_ = Xb + (size_t)(s) * 32 * N_;                          \
      const float* p_ = Pb + (size_t)(s) * 32 * N_;                          \
      X0 = *(const float2*)x_;                                               \
      X1 = *(const float2*)(x_ + N_);                                        \
      P0 = *(const float2*)p_;                                               \
      P1 = *(const float2*)(p_ + N_);                                        \
    }
#define WRITEA(X0, X1, P0, P1, bufp)                                         \
    {                                                                        \
      *(uint32_t*)&shpool[bufp][2 * q2][2 * cqs]     = pk2(X0.x + P0.x, X1.x + P1.x); \
      *(uint32_t*)&shpool[bufp][2 * q2 + 1][2 * cqs] = pk2(X0.y + P0.y, X1.y + P1.y); \
      *(uint32_t*)&shpool[(bufp) + 1][2 * q2][2 * cqs]     = pk2(X0.x, X1.x); \
      *(uint32_t*)&shpool[(bufp) + 1][2 * q2 + 1][2 * cqs] = pk2(X0.y, X1.y); \
    }
#define COMPUTE(bufp)                                                        \
    {                                                                        \
      _Pragma("unroll") for (int nf = 0; nf < 4; ++nf) {                     \
        const int r_ = nf * 16 + c15;                                        \
        const int o_ = (g ^ ((r_ >> 3) & 3)) * 8;                            \
        const bf16x8 Fp = *(const bf16x8*)&shpool[bufp][r_][o_];             \
        const bf16x8 Fv = *(const bf16x8*)&shpool[(bufp) + 1][r_][o_];       \
        _Pragma("unroll") for (int cf = 0; cf < 2; ++cf) {                   \
          acck[cf * 4 + nf] = __builtin_amdgcn_mfma_f32_16x16x32_bf16(       \
              Wk[cf], Fp, acck[cf * 4 + nf], 0, 0, 0);                       \
          accv[nf * 2 + cf] = __builtin_amdgcn_mfma_f32_16x16x32_bf16(       \
              Fv, Wv[cf], accv[nf * 2 + cf], 0, 0, 0);                       \
        }                                                                    \
      }                                                                      \
    }

    // prologue: acts(0) -> A, acts(1) -> B
    LOADA(xA0, xA1, pA0, pA1, 0);
    LOADA(xB0, xB1, pB0, pB1, 1);
    // s=0
    LOADW(0); WRITEA(xA0, xA1, pA0, pA1, 0); LOADA(xA0, xA1, pA0, pA1, 2);
    lgkm0_barrier(); COMPUTE(0); __builtin_amdgcn_sched_barrier(0);
    // s=1
    LOADW(1); WRITEA(xB0, xB1, pB0, pB1, 2); LOADA(xB0, xB1, pB0, pB1, 3);
    lgkm0_barrier(); COMPUTE(2); __builtin_amdgcn_sched_barrier(0);
    // s=2
    LOADW(2); WRITEA(xA0, xA1, pA0, pA1, 0); LOADA(xA0, xA1, pA0, pA1, 4);
    lgkm0_barrier(); COMPUTE(0); __builtin_amdgcn_sched_barrier(0);
    // s=3
    LOADW(3); WRITEA(xB0, xB1, pB0, pB1, 2); LOADA(xB0, xB1, pB0, pB1, 5);
    lgkm0_barrier(); COMPUTE(2); __builtin_amdgcn_sched_barrier(0);
    // s=4
    LOADW(4); WRITEA(xA0, xA1, pA0, pA1, 0); LOADA(xA0, xA1, pA0, pA1, 6);
    lgkm0_barrier(); COMPUTE(0); __builtin_amdgcn_sched_barrier(0);
    // s=5
    LOADW(5); WRITEA(xB0, xB1, pB0, pB1, 2); LOADA(xB0, xB1, pB0, pB1, 7);
    lgkm0_barrier(); COMPUTE(2); __builtin_amdgcn_sched_barrier(0);
    // s=6
    LOADW(6); WRITEA(xA0, xA1, pA0, pA1, 0);
    lgkm0_barrier(); COMPUTE(0); __builtin_amdgcn_sched_barrier(0);
    // s=7
    LOADW(7); WRITEA(xB0, xB1, pB0, pB1, 2);
    lgkm0_barrier(); COMPUTE(2); __builtin_amdgcn_sched_barrier(0);

#undef LOADW
#undef LOADA
#undef WRITEA
#undef COMPUTE

    // K store: lane holds 4 consecutive dk at n = n0 + nf*16 + c15
    uint16_t* Kp = Kh + (size_t)(b * H_ + w) * N_ * D_;
#pragma unroll
    for (int cf = 0; cf < 2; ++cf)
#pragma unroll
      for (int nf = 0; nf < 4; ++nf) {
        const f32x4 a = acck[cf * 4 + nf];
        uint2 pkv;
        pkv.x = pk2(a[0], a[1]);
        pkv.y = pk2(a[2], a[3]);
        *(uint2*)&Kp[(size_t)(n0 + nf * 16 + c15) * D_ + cf * 16 + 4 * g] = pkv;
      }
    // V store: lane holds 4 consecutive n at dv = cf*16 + c15
    uint16_t* Vp = Vh + (size_t)(b * H_ + w) * D_ * N_;
#pragma unroll
    for (int nf = 0; nf < 4; ++nf)
#pragma unroll
      for (int cf = 0; cf < 2; ++cf) {
        const f32x4 a = accv[nf * 2 + cf];
        uint2 pkv;
        pkv.x = pk2(a[0], a[1]);
        pkv.y = pk2(a[2], a[3]);
        *(uint2*)&Vp[(size_t)(cf * 16 + c15) * N_ + n0 + nf * 16 + 4 * g] = pkv;
      }
  } else {
    // ---- Q projection: 8 blocks x 64 q-rows ----
    const int qb = bid;
    const int q0g = qb * 64;
    const int b = q0g >> 8, q0 = q0g & 255;
    const int r = t >> 3, c0 = (t & 7) * 32, s = t & 7;
    const float* Qrow = queries + (size_t)(q0g + r) * C_ + c0;
    const float* Erow = qembed + (size_t)(q0g + r) * C_ + c0;
#pragma unroll
    for (int ph = 0; ph < 2; ++ph) {
      float4 a4[4], e4[4];
#pragma unroll
      for (int k = 0; k < 4; ++k) a4[k] = reinterpret_cast<const float4*>(Qrow + ph * 16)[k];
#pragma unroll
      for (int k = 0; k < 4; ++k) e4[k] = reinterpret_cast<const float4*>(Erow + ph * 16)[k];
      const float* af = reinterpret_cast<const float*>(a4);
      const float* ef = reinterpret_cast<const float*>(e4);
#pragma unroll
      for (int i = 0; i < 16; ++i) {
        const int cl = ph * 16 + i;
        const int col = cl ^ (8 * ((r >> 3) & 3));
        shpool[s][r][col] = bfbits(af[i] + ef[i]);
      }
      __builtin_amdgcn_sched_barrier(0);
    }
    lgkm0_barrier();

    const int w = wid;  // head = w
    f32x4 acc[4][2];
#pragma unroll
    for (int nf = 0; nf < 2; ++nf) {
      const float bv = bias[w * 32 + nf * 16 + c15];
      const f32x4 iv = {bv, bv, bv, bv};
#pragma unroll
      for (int qf = 0; qf < 4; ++qf) acc[qf][nf] = iv;
    }
#pragma unroll
    for (int s8 = 0; s8 < 8; ++s8) {
      bf16x8 Bf[2];
#pragma unroll
      for (int nf = 0; nf < 2; ++nf)
        Bf[nf] = *reinterpret_cast<const bf16x8*>(
            wkv + (size_t)(w * 32 + nf * 16 + c15) * C_ + s8 * 32 + g * 8);
#pragma unroll
      for (int qf = 0; qf < 4; ++qf) {
        const int rr = qf * 16 + c15;
        const bf16x8 Af = *reinterpret_cast<const bf16x8*>(
            &shpool[s8][rr][8 * (g ^ ((rr >> 3) & 3))]);
#pragma unroll
        for (int nf = 0; nf < 2; ++nf)
          acc[qf][nf] = __builtin_amdgcn_mfma_f32_16x16x32_bf16(Af, Bf[nf], acc[qf][nf], 0, 0, 0);
      }
    }
#pragma unroll
    for (int qf = 0; qf < 4; ++qf)
#pragma unroll
      for (int nf = 0; nf < 2; ++nf)
#pragma unroll
        for (int j = 0; j < 4; ++j) {
          const int q = q0 + qf * 16 + 4 * g + j;
          const int dk = nf * 16 + c15;
          Qb[((size_t)(b * H_ + w) * Q_ + q) * D_ + dk] = bfbits(acc[qf][nf][j] * SCALEQ);
        }
  }
}

// ---------------------------------------------------------------------------
// Kernel 3: attention over an N-chunk of 512 keys, all 256 queries of one
// (b,h). ctx partials now Q-MAJOR: ctxp[bq][h][nc][dv], lsum[bq][h][nc]
// (epilogue reads become contiguous 16KB streams).
// ---------------------------------------------------------------------------
__global__ __launch_bounds__(512) void attn(const uint16_t* __restrict__ Qb,
                                            const uint16_t* __restrict__ Kh,
                                            const uint16_t* __restrict__ Vh,
                                            const uint32_t* __restrict__ mb,
                                            uint16_t* __restrict__ ctx_part,
                                            float* __restrict__ lsum_part) {
  const int bid = blockIdx.x;
  const int nc = bid & 31, h = (bid >> 5) & 7, b = bid >> 8;
  const int t = threadIdx.x, wid = t >> 6, lane = t & 63;
  const int g = lane >> 4, c15 = lane & 15;
  const int qw0 = wid * 32;
  const int nbase = nc * (N_ / NC_);
  constexpr int SS = (N_ / NC_) / 128;

  __shared__ __align__(16) uint16_t kst[2][128][40];
  __shared__ __align__(16) uint16_t vst[2][32][136];
  __shared__ __align__(16) uint16_t plds[8][32][40];

  const uint16_t* Qp = Qb + (size_t)(b * H_ + h) * Q_ * D_;
  bf16x8 qfr[2];
#pragma unroll
  for (int qf = 0; qf < 2; ++qf)
    qfr[qf] = *reinterpret_cast<const bf16x8*>(Qp + (size_t)(qw0 + qf * 16 + c15) * D_ + g * 8);

  f32x4 acc[2][2];
  const f32x4 zero4 = {0.f, 0.f, 0.f, 0.f};
#pragma unroll
  for (int qf = 0; qf < 2; ++qf)
#pragma unroll
    for (int dvf = 0; dvf < 2; ++dvf) acc[qf][dvf] = zero4;
  float lsum[2][4] = {};

  const uint32_t* mrow = mb + (size_t)b * Q_ * (N_ / 32);

  const int krow = t >> 2, kch = t & 3;
  const uint16_t* ksrc = Kh + ((size_t)(b * H_ + h) * N_ + nbase + krow) * 32 + kch * 8;
  const int vrow = t >> 4, vch = t & 15;
  const uint16_t* vsrc = Vh + ((size_t)(b * H_ + h) * 32 + vrow) * N_ + nbase + vch * 8;

  uint4 kreg = *(const uint4*)ksrc;
  uint4 vreg = *(const uint4*)vsrc;

  int cur = 0;
  for (int ss = 0; ss < SS; ++ss) {
    *(uint4*)&kst[cur][krow][kch * 8] = kreg;
    *(uint4*)&vst[cur][vrow][vch * 8] = vreg;
    if (ss < SS - 1) {
      kreg = *(const uint4*)(ksrc + (size_t)(ss + 1) * 128 * 32);
      vreg = *(const uint4*)(vsrc + (ss + 1) * 128);
    }
    lgkm0_barrier();

    const int nstart = nbase + ss * 128;
#pragma unroll
    for (int half = 0; half < 2; ++half) {
      uint32_t mw[2][4][2];
#pragma unroll
      for (int qf = 0; qf < 2; ++qf)
#pragma unroll
        for (int j = 0; j < 4; ++j) {
          const int q = qw0 + qf * 16 + 4 * g + j;
          const uint2 u = *reinterpret_cast<const uint2*>(
              &mrow[(size_t)q * (N_ / 32) + (nstart >> 5) + half * 2]);
          mw[qf][j][0] = u.x;
          mw[qf][j][1] = u.y;
        }
#pragma unroll
      for (int s2 = 0; s2 < 2; ++s2) {
        const int sub = half * 2 + s2;
        const int nl0 = sub * 32;
        bf16x8 kfr[2];
#pragma unroll
        for (int nf = 0; nf < 2; ++nf)
          kfr[nf] = *reinterpret_cast<const bf16x8*>(&kst[cur][nl0 + nf * 16 + c15][g * 8]);
        f32x4 s[2][2];
#pragma unroll
        for (int qf = 0; qf < 2; ++qf)
#pragma unroll
          for (int nf = 0; nf < 2; ++nf)
            s[qf][nf] = __builtin_amdgcn_mfma_f32_16x16x32_bf16(qfr[qf], kfr[nf], zero4, 0, 0, 0);

#pragma unroll
        for (int qf = 0; qf < 2; ++qf) {
#pragma unroll
          for (int j = 0; j < 4; ++j) {
            const uint32_t wmask = mw[qf][j][s2];
#pragma unroll
            for (int nf = 0; nf < 2; ++nf) {
              const int bit = nf * 16 + c15;
              const float p = ((wmask >> bit) & 1u) ? 0.0f : exp2f(s[qf][nf][j]);
              lsum[qf][j] += p;
              plds[wid][qf * 16 + 4 * g + j][nf * 16 + c15] = bfbits(p);
            }
          }
        }
        __asm__ volatile("s_waitcnt lgkmcnt(0)" ::: "memory");
#pragma unroll
        for (int qf = 0; qf < 2; ++qf) {
          const bf16x8 pa = *reinterpret_cast<const bf16x8*>(&plds[wid][qf * 16 + c15][g * 8]);
#pragma unroll
          for (int dvf = 0; dvf < 2; ++dvf) {
            const bf16x8 vb =
                *reinterpret_cast<const bf16x8*>(&vst[cur][dvf * 16 + c15][nl0 + g * 8]);
            acc[qf][dvf] = __builtin_amdgcn_mfma_f32_16x16x32_bf16(pa, vb, acc[qf][dvf], 0, 0, 0);
          }
        }
      }
    }
    __builtin_amdgcn_sched_barrier(0);
    cur ^= 1;
  }

#pragma unroll
  for (int qf = 0; qf < 2; ++qf)
#pragma unroll
    for (int j = 0; j < 4; ++j) {
      float v = lsum[qf][j];
      v += __shfl_xor(v, 1, 64);
      v += __shfl_xor(v, 2, 64);
      v += __shfl_xor(v, 4, 64);
      v += __shfl_xor(v, 8, 64);
      lsum[qf][j] = v;
    }

  // Q-major partial stores: ctxp[((bq*H + h)*NC + nc)*D + dv], bq = b*Q + q
#pragma unroll
  for (int qf = 0; qf < 2; ++qf)
#pragma unroll
    for (int dvf = 0; dvf < 2; ++dvf)
#pragma unroll
      for (int j = 0; j < 4; ++j) {
        const int q = qw0 + qf * 16 + 4 * g + j;
        const size_t base = (((size_t)(b * Q_ + q) * H_ + h) * NC_ + nc) * D_;
        ctx_part[base + dvf * 16 + c15] = bfbits(acc[qf][dvf][j]);
      }
  if (c15 == 0) {
#pragma unroll
    for (int qf = 0; qf < 2; ++qf)
#pragma unroll
      for (int j = 0; j < 4; ++j) {
        const int q = qw0 + qf * 16 + 4 * g + j;
        lsum_part[((size_t)(b * Q_ + q) * H_ + h) * NC_ + nc] = lsum[qf][j];
      }
  }
}

// ---------------------------------------------------------------------------
// Kernel 4: combine partials (Q-major, contiguous per row) + out_proj (woT)
// + residual + LayerNorm.
// ---------------------------------------------------------------------------
__global__ __launch_bounds__(256) void epilogue(const uint16_t* __restrict__ ctx_part,
                                                const float* __restrict__ lsum_part,
                                                const float* __restrict__ queries,
                                                const float* __restrict__ woT,
                                                const float* __restrict__ bo,
                                                const float* __restrict__ gamma,
                                                const float* __restrict__ beta,
                                                float* __restrict__ out) {
  const int bq = blockIdx.x;
  const int t = threadIdx.x;
  const int h = t >> 5, dv = t & 31;
  // ctxp row for this bq: [h][nc][dv] contiguous (8*32*32 bf16 = 16 KB)
  const uint16_t* crow = ctx_part + (size_t)bq * H_ * NC_ * D_;
  const float* lrow = lsum_part + (size_t)bq * H_ * NC_;
  float cs = 0.f, ls = 0.f;
#pragma unroll 8
  for (int k = 0; k < NC_; ++k) {
    cs += bf2f(crow[((size_t)h * NC_ + k) * D_ + dv]);
    ls += lrow[h * NC_ + k];
  }
  __shared__ float ctxrow[C_];
  ctxrow[t] = cs / ls;
  __syncthreads();
  float acc = bo[t];
#pragma unroll 8
  for (int j = 0; j < C_; ++j) acc = fmaf(ctxrow[j], woT[(size_t)j * C_ + t], acc);
  const float x = queries[(size_t)bq * C_ + t] + acc;
  float s1 = x, s2 = x * x;
  for (int o = 32; o > 0; o >>= 1) {
    s1 += __shfl_down(s1, o, 64);
    s2 += __shfl_down(s2, o, 64);
  }
  __shared__ float r1[4], r2[4];
  if ((t & 63) == 0) { r1[t >> 6] = s1; r2[t >> 6] = s2; }
  __syncthreads();
  const float mu = (r1[0] + r1[1] + r1[2] + r1[3]) * (1.0f / C_);
  const float e2 = (r2[0] + r2[1] + r2[2] + r2[3]) * (1.0f / C_);
  const float var = e2 - mu * mu;
  out[(size_t)bq * C_ + t] = (x - mu) * rsqrtf(var + 1e-5f) * gamma[t] + beta[t];
}

extern "C" void kernel_launch(void* const* d_in, const int* in_sizes, int n_in,
                              void* d_out, int out_size, void* d_ws, size_t ws_size,
                              hipStream_t stream) {
  const float* queries    = (const float*)d_in[0];
  const float* vidfeat    = (const float*)d_in[1];
  const float* vidmask    = (const float*)d_in[2];
  const float* posembed   = (const float*)d_in[3];
  const float* queryembed = (const float*)d_in[4];
  const float* inw        = (const float*)d_in[5];
  const float* inb        = (const float*)d_in[6];
  const float* outw       = (const float*)d_in[7];
  const float* outb       = (const float*)d_in[8];
  const float* gamma      = (const float*)d_in[9];
  const float* beta       = (const float*)d_in[10];
  float* out = (float*)d_out;

  char* ws = (char*)d_ws;
  size_t off = 0;
  uint16_t* Qb   = (uint16_t*)(ws + off); off += (size_t)B_ * H_ * Q_ * D_ * 2;      // 256 KB
  uint16_t* Kh   = (uint16_t*)(ws + off); off += (size_t)B_ * H_ * N_ * D_ * 2;      // 16.78 MB
  uint16_t* Vh   = (uint16_t*)(ws + off); off += (size_t)B_ * H_ * D_ * N_ * 2;      // 16.78 MB
  uint32_t* mb   = (uint32_t*)(ws + off); off += (size_t)B_ * Q_ * (N_ / 32) * 4;    // 1 MB
  uint16_t* wkv  = (uint16_t*)(ws + off); off += (size_t)768 * C_ * 2;               // 384 KB
  float* woT     = (float*)(ws + off);    off += (size_t)C_ * C_ * 4;                // 256 KB
  uint16_t* ctxp = (uint16_t*)(ws + off); off += (size_t)B_ * Q_ * H_ * NC_ * D_ * 2;// 8.39 MB
  float* lsump   = (float*)(ws + off);    off += (size_t)B_ * Q_ * H_ * NC_ * 4;     // 1 MB

  prep<<<dim3(672), dim3(256), 0, stream>>>(inw, outw, vidmask, wkv, woT, mb);
  kvqproj<<<dim3(520), dim3(512), 0, stream>>>(vidfeat, posembed, queries, queryembed,
                                               wkv, inb, Kh, Vh, Qb);
  attn<<<dim3(B_ * H_ * NC_), dim3(512), 0, stream>>>(Qb, Kh, Vh, mb, ctxp, lsump);
  epilogue<<<dim3(B_ * Q_), dim3(256), 0, stream>>>(ctxp, lsump, queries, woT, outb,
                                                    gamma, beta, out);
}

// Round 18
// 89.727 us; speedup vs baseline: 1.3525x; 1.0551x over previous
//
#include <hip/hip_runtime.h>
#include <stdint.h>

// CrossAttentionLayer: B=2, Q=256, N=16384, C=256, H=8, d=32
#define B_ 2
#define Q_ 256
#define N_ 16384
#define C_ 256
#define H_ 8
#define D_ 32
#define NC_ 32                       // attention split-N chunks (512 keys/block)
#define SCALEQ 0.2550542176432015f   // (1/sqrt(32)) * log2(e)  [exp -> exp2]

typedef __bf16 bf16x8 __attribute__((ext_vector_type(8)));
typedef float f32x4 __attribute__((ext_vector_type(4)));

__device__ __forceinline__ uint16_t bfbits(float f) {
  union { __bf16 h; uint16_t u; } c; c.h = (__bf16)f; return c.u;
}
__device__ __forceinline__ float bf2f(uint16_t u) {
  union { uint32_t u; float f; } c; c.u = (uint32_t)u << 16;
  return c.f;
}
__device__ __forceinline__ uint32_t pk2(float a, float b) {
  union { struct { uint16_t lo, hi; } s; uint32_t u; } c;
  c.s.lo = bfbits(a); c.s.hi = bfbits(b);
  return c.u;  // fuses to v_cvt_pk_bf16_f32
}
__device__ __forceinline__ void lgkm0_barrier() {
  __builtin_amdgcn_sched_barrier(0);
  asm volatile("s_waitcnt lgkmcnt(0)" ::: "memory");
  __builtin_amdgcn_sched_barrier(0);
  __builtin_amdgcn_s_barrier();
  __builtin_amdgcn_sched_barrier(0);
}

// ---------------------------------------------------------------------------
// Kernel 1 "prep": blocks 0..95: in_proj_w (768x256) -> bf16; 96..159:
// woT = out_proj_w^T; 160..671: pack vid_mask -> bitmask (bit=1 => blocked)
// with all-blocked fallback.  (unchanged, verified)
// ---------------------------------------------------------------------------
__global__ __launch_bounds__(256) void prep(const float* __restrict__ inw,
                                            const float* __restrict__ outw,
                                            const float* __restrict__ vm,
                                            uint16_t* __restrict__ wb,
                                            float* __restrict__ woT,
                                            uint32_t* __restrict__ mb) {
  __shared__ __align__(16) char sh[4352];
  const int bid = blockIdx.x;
  const int t = threadIdx.x;
  if (bid < 96) {
    const int i = (bid * 256 + t) * 8;
    const float4 a = *reinterpret_cast<const float4*>(inw + i);
    const float4 b = *reinterpret_cast<const float4*>(inw + i + 4);
    ushort4 lo = {bfbits(a.x), bfbits(a.y), bfbits(a.z), bfbits(a.w)};
    ushort4 hi = {bfbits(b.x), bfbits(b.y), bfbits(b.z), bfbits(b.w)};
    *reinterpret_cast<ushort4*>(wb + i) = lo;
    *reinterpret_cast<ushort4*>(wb + i + 4) = hi;
  } else if (bid < 160) {
    float(*s)[33] = reinterpret_cast<float(*)[33]>(sh);
    const int bb = bid - 96;
    const int bx = bb & 7, by = bb >> 3;
    const int r0 = by * 32, c0 = bx * 32;
    const int tr = t >> 5, tc = t & 31;
#pragma unroll
    for (int k = 0; k < 4; ++k)
      s[tr + 8 * k][tc] = outw[(size_t)(r0 + tr + 8 * k) * 256 + c0 + tc];
    __syncthreads();
#pragma unroll
    for (int k = 0; k < 4; ++k)
      woT[(size_t)(c0 + tr + 8 * k) * 256 + r0 + tc] = s[tc][tr + 8 * k];
  } else {
    uint8_t(*nib)[256] = reinterpret_cast<uint8_t(*)[256]>(sh);
    __shared__ int wcnt[4];
    __shared__ int tot;
    const int bq = bid - 160;
    const float* row = vm + (size_t)bq * N_;
    const int lane = t & 63;
    int cnt = 0;
#pragma unroll
    for (int i = 0; i < 16; ++i) {
      const float4 v = *reinterpret_cast<const float4*>(&row[i * 1024 + 4 * t]);
      const uint32_t nb = (v.x < 0.5f ? 1u : 0u) | (v.y < 0.5f ? 2u : 0u) |
                          (v.z < 0.5f ? 4u : 0u) | (v.w < 0.5f ? 8u : 0u);
      nib[i][t] = (uint8_t)nb;
      cnt += __popc(nb);
    }
    for (int o = 32; o > 0; o >>= 1) cnt += __shfl_down(cnt, o, 64);
    if (lane == 0) wcnt[t >> 6] = cnt;
    __syncthreads();
    if (t == 0) tot = wcnt[0] + wcnt[1] + wcnt[2] + wcnt[3];
    __syncthreads();
    const bool allb = (tot == N_);
    uint32_t* dst = mb + (size_t)bq * 512;
#pragma unroll
    for (int k = 0; k < 2; ++k) {
      const int w = k * 256 + t;
      const int i = w >> 5, tw = w & 31;
      const uint2 u = *reinterpret_cast<const uint2*>(&nib[i][8 * tw]);
      uint32_t y0 = u.x & 0x0F0F0F0Fu; y0 = y0 | (y0 >> 4);
      uint32_t y1 = u.y & 0x0F0F0F0Fu; y1 = y1 | (y1 >> 4);
      const uint32_t word = (y0 & 0xFFu) | (((y0 >> 16) & 0xFFu) << 8) |
                            ((y1 & 0xFFu) << 16) | (((y1 >> 16) & 0xFFu) << 24);
      dst[w] = allb ? 0u : word;
    }
  }
}

// ---------------------------------------------------------------------------
// Kernel 2 "kvqproj" (R17): 1024-thr fused K+V blocks, n-tile = 128.
// Staging reads are 512B-contiguous per wave-instruction (cp = t>>6 is
// wave-uniform; n2 = lane): granularity 2x vs the 256B base at IDENTICAL
// byte count, VGPR envelope (acc 64) and waves/SIMD (4).
//  bid 0..7   : Q projection (waves 0..7 active; 8..15 just hit the barrier)
//  bid 8..263 : KV blocks; wave w<8 = K head w, w>=8 = V head w-8.
// Outputs: Kh [b][h][n][32], Vh [b][h][32][n]. Qb pre-scaled by SCALEQ.
// ---------------------------------------------------------------------------
__global__ __launch_bounds__(1024, 4) void kvqproj(const float* __restrict__ vf,
                                                   const float* __restrict__ pe,
                                                   const float* __restrict__ queries,
                                                   const float* __restrict__ qembed,
                                                   const uint16_t* __restrict__ wkv,
                                                   const float* __restrict__ bias,
                                                   uint16_t* __restrict__ Kh,
                                                   uint16_t* __restrict__ Vh,
                                                   uint16_t* __restrict__ Qb) {
  // [arr(XP/XV)][buf][n][col] = 40 KB; qproj reuses as [8][64][40]
  __shared__ __align__(16) uint16_t shp[2][2][128][40];
  const int bid = blockIdx.x;
  const int t = threadIdx.x, wid = t >> 6, lane = t & 63;
  const int g = lane >> 4, c15 = lane & 15;

  if (bid >= 8) {
    const int kb = bid - 8;
    const int b = kb >> 7, nt = kb & 127;
    const int n0 = nt * 128;
    const bool isK = wid < 8;
    const int w = wid & 7;  // head

    const uint16_t* Wsec = wkv + (size_t)((isK ? 256 : 512) + w * 32 + c15) * C_;

    f32x4 acc[16];  // K: acc[cf*8+nf] (D[cout][n]); V: acc[nf*2+cf] (D[n][cout])
    if (isK) {
#pragma unroll
      for (int cf = 0; cf < 2; ++cf) {
        f32x4 iv;
#pragma unroll
        for (int j = 0; j < 4; ++j) iv[j] = bias[256 + w * 32 + cf * 16 + 4 * g + j];
#pragma unroll
        for (int nf = 0; nf < 8; ++nf) acc[cf * 8 + nf] = iv;
      }
    } else {
#pragma unroll
      for (int cf = 0; cf < 2; ++cf) {
        const float bv = bias[512 + w * 32 + cf * 16 + c15];
        const f32x4 iv = {bv, bv, bv, bv};
#pragma unroll
        for (int nf = 0; nf < 8; ++nf) acc[nf * 2 + cf] = iv;
      }
    }

    // staging map: cp = t>>6 (cin pair, WAVE-UNIFORM), n2 = lane (n pair)
    const int cp = t >> 6, n2 = lane;
    const float* Xb = vf + ((size_t)b * C_ + 2 * cp) * N_ + n0 + 2 * n2;
    const float* Pb = pe + ((size_t)b * C_ + 2 * cp) * N_ + n0 + 2 * n2;
    const int cps = cp ^ (((n2 >> 2) & 3) << 2);  // 16B-block XOR swizzle

    float2 xA0, xA1, pA0, pA1, xB0, xB1, pB0, pB1;
    bf16x8 W[2];

#define LOADW(s)                                                             \
    {                                                                        \
      _Pragma("unroll") for (int cf = 0; cf < 2; ++cf)                       \
          W[cf] = *(const bf16x8*)(Wsec + (size_t)cf * 16 * C_ + (s) * 32 + g * 8); \
    }
#define LOADA(X0, X1, P0, P1, s)                                             \
    {                                                                        \
      const float* x_ = Xb + (size_t)(s) * 32 * N_;                          \
      const float* p_ = Pb + (size_t)(s) * 32 * N_;                          \
      X0 = *(const float2*)x_;                                               \
      X1 = *(const float2*)(x_ + N_);                                        \
      P0 = *(const float2*)p_;                                               \
      P1 = *(const float2*)(p_ + N_);                                        \
    }
#define WRITEA(X0, X1, P0, P1, buf)                                          \
    {                                                                        \
      *(uint32_t*)&shp[0][buf][2 * n2][2 * cps]     = pk2(X0.x + P0.x, X1.x + P1.x); \
      *(uint32_t*)&shp[0][buf][2 * n2 + 1][2 * cps] = pk2(X0.y + P0.y, X1.y + P1.y); \
      *(uint32_t*)&shp[1][buf][2 * n2][2 * cps]     = pk2(X0.x, X1.x);       \
      *(uint32_t*)&shp[1][buf][2 * n2 + 1][2 * cps] = pk2(X0.y, X1.y);       \
    }
#define COMPUTE(buf)                                                         \
    {                                                                        \
      _Pragma("unroll") for (int nf = 0; nf < 8; ++nf) {                     \
        const int r_ = nf * 16 + c15;                                        \
        const int o_ = (g ^ ((r_ >> 3) & 3)) * 8;                            \
        if (isK) {                                                           \
          const bf16x8 Fp = *(const bf16x8*)&shp[0][buf][r_][o_];            \
          _Pragma("unroll") for (int cf = 0; cf < 2; ++cf)                   \
              acc[cf * 8 + nf] = __builtin_amdgcn_mfma_f32_16x16x32_bf16(    \
                  W[cf], Fp, acc[cf * 8 + nf], 0, 0, 0);                     \
        } else {                                                             \
          const bf16x8 Fv = *(const bf16x8*)&shp[1][buf][r_][o_];            \
          _Pragma("unroll") for (int cf = 0; cf < 2; ++cf)                   \
              acc[nf * 2 + cf] = __builtin_amdgcn_mfma_f32_16x16x32_bf16(    \
                  Fv, W[cf], acc[nf * 2 + cf], 0, 0, 0);                     \
        }                                                                    \
      }                                                                      \
    }

    // prologue: acts(0) -> A, acts(1) -> B
    LOADA(xA0, xA1, pA0, pA1, 0);
    LOADA(xB0, xB1, pB0, pB1, 1);
    // s=0
    LOADW(0); WRITEA(xA0, xA1, pA0, pA1, 0); LOADA(xA0, xA1, pA0, pA1, 2);
    lgkm0_barrier(); COMPUTE(0); __builtin_amdgcn_sched_barrier(0);
    // s=1
    LOADW(1); WRITEA(xB0, xB1, pB0, pB1, 1); LOADA(xB0, xB1, pB0, pB1, 3);
    lgkm0_barrier(); COMPUTE(1); __builtin_amdgcn_sched_barrier(0);
    // s=2
    LOADW(2); WRITEA(xA0, xA1, pA0, pA1, 0); LOADA(xA0, xA1, pA0, pA1, 4);
    lgkm0_barrier(); COMPUTE(0); __builtin_amdgcn_sched_barrier(0);
    // s=3
    LOADW(3); WRITEA(xB0, xB1, pB0, pB1, 1); LOADA(xB0, xB1, pB0, pB1, 5);
    lgkm0_barrier(); COMPUTE(1); __builtin_amdgcn_sched_barrier(0);
    // s=4
    LOADW(4); WRITEA(xA0, xA1, pA0, pA1, 0); LOADA(xA0, xA1, pA0, pA1, 6);
    lgkm0_barrier(); COMPUTE(0); __builtin_amdgcn_sched_barrier(0);
    // s=5
    LOADW(5); WRITEA(xB0, xB1, pB0, pB1, 1); LOADA(xB0, xB1, pB0, pB1, 7);
    lgkm0_barrier(); COMPUTE(1); __builtin_amdgcn_sched_barrier(0);
    // s=6
    LOADW(6); WRITEA(xA0, xA1, pA0, pA1, 0);
    lgkm0_barrier(); COMPUTE(0); __builtin_amdgcn_sched_barrier(0);
    // s=7
    LOADW(7); WRITEA(xB0, xB1, pB0, pB1, 1);
    lgkm0_barrier(); COMPUTE(1); __builtin_amdgcn_sched_barrier(0);

#undef LOADW
#undef LOADA
#undef WRITEA
#undef COMPUTE

    if (isK) {
      // K store: lane holds 4 consecutive dk at n = n0 + nf*16 + c15
      uint16_t* Kp = Kh + (size_t)(b * H_ + w) * N_ * D_;
#pragma unroll
      for (int cf = 0; cf < 2; ++cf)
#pragma unroll
        for (int nf = 0; nf < 8; ++nf) {
          const f32x4 a = acc[cf * 8 + nf];
          uint2 pkv;
          pkv.x = pk2(a[0], a[1]);
          pkv.y = pk2(a[2], a[3]);
          *(uint2*)&Kp[(size_t)(n0 + nf * 16 + c15) * D_ + cf * 16 + 4 * g] = pkv;
        }
    } else {
      // V store: lane holds 4 consecutive n at dv = cf*16 + c15
      uint16_t* Vp = Vh + (size_t)(b * H_ + w) * D_ * N_;
#pragma unroll
      for (int nf = 0; nf < 8; ++nf)
#pragma unroll
        for (int cf = 0; cf < 2; ++cf) {
          const f32x4 a = acc[nf * 2 + cf];
          uint2 pkv;
          pkv.x = pk2(a[0], a[1]);
          pkv.y = pk2(a[2], a[3]);
          *(uint2*)&Vp[(size_t)(cf * 16 + c15) * N_ + n0 + nf * 16 + 4 * g] = pkv;
        }
    }
  } else {
    // ---- Q projection: 8 blocks x 64 q-rows (waves 0..7 active) ----
    uint16_t(*qv)[64][40] = reinterpret_cast<uint16_t(*)[64][40]>(&shp[0][0][0][0]);
    const int qb = bid;
    const int q0g = qb * 64;
    const int b = q0g >> 8, q0 = q0g & 255;
    if (t < 512) {
      const int r = t >> 3, c0 = (t & 7) * 32, s = t & 7;
      const float* Qrow = queries + (size_t)(q0g + r) * C_ + c0;
      const float* Erow = qembed + (size_t)(q0g + r) * C_ + c0;
#pragma unroll
      for (int ph = 0; ph < 2; ++ph) {
        float4 a4[4], e4[4];
#pragma unroll
        for (int k = 0; k < 4; ++k) a4[k] = reinterpret_cast<const float4*>(Qrow + ph * 16)[k];
#pragma unroll
        for (int k = 0; k < 4; ++k) e4[k] = reinterpret_cast<const float4*>(Erow + ph * 16)[k];
        const float* af = reinterpret_cast<const float*>(a4);
        const float* ef = reinterpret_cast<const float*>(e4);
#pragma unroll
        for (int i = 0; i < 16; ++i) {
          const int cl = ph * 16 + i;
          const int col = cl ^ (8 * ((r >> 3) & 3));
          qv[s][r][col] = bfbits(af[i] + ef[i]);
        }
        __builtin_amdgcn_sched_barrier(0);
      }
    }
    lgkm0_barrier();
    if (t < 512) {
      const int w = wid;  // head = w (0..7)
      f32x4 acc[4][2];
#pragma unroll
      for (int nf = 0; nf < 2; ++nf) {
        const float bv = bias[w * 32 + nf * 16 + c15];
        const f32x4 iv = {bv, bv, bv, bv};
#pragma unroll
        for (int qf = 0; qf < 4; ++qf) acc[qf][nf] = iv;
      }
#pragma unroll
      for (int s8 = 0; s8 < 8; ++s8) {
        bf16x8 Bf[2];
#pragma unroll
        for (int nf = 0; nf < 2; ++nf)
          Bf[nf] = *reinterpret_cast<const bf16x8*>(
              wkv + (size_t)(w * 32 + nf * 16 + c15) * C_ + s8 * 32 + g * 8);
#pragma unroll
        for (int qf = 0; qf < 4; ++qf) {
          const int rr = qf * 16 + c15;
          const bf16x8 Af = *reinterpret_cast<const bf16x8*>(
              &qv[s8][rr][8 * (g ^ ((rr >> 3) & 3))]);
#pragma unroll
          for (int nf = 0; nf < 2; ++nf)
            acc[qf][nf] = __builtin_amdgcn_mfma_f32_16x16x32_bf16(Af, Bf[nf], acc[qf][nf], 0, 0, 0);
        }
      }
#pragma unroll
      for (int qf = 0; qf < 4; ++qf)
#pragma unroll
        for (int nf = 0; nf < 2; ++nf)
#pragma unroll
          for (int j = 0; j < 4; ++j) {
            const int q = q0 + qf * 16 + 4 * g + j;
            const int dk = nf * 16 + c15;
            Qb[((size_t)(b * H_ + w) * Q_ + q) * D_ + dk] = bfbits(acc[qf][nf][j] * SCALEQ);
          }
    }
  }
}

// ---------------------------------------------------------------------------
// Kernel 3: attention over an N-chunk of 512 keys, all 256 queries of one
// (b,h). Q-major partials (R17 winner, unchanged).
// ---------------------------------------------------------------------------
__global__ __launch_bounds__(512) void attn(const uint16_t* __restrict__ Qb,
                                            const uint16_t* __restrict__ Kh,
                                            const uint16_t* __restrict__ Vh,
                                            const uint32_t* __restrict__ mb,
                                            uint16_t* __restrict__ ctx_part,
                                            float* __restrict__ lsum_part) {
  const int bid = blockIdx.x;
  const int nc = bid & 31, h = (bid >> 5) & 7, b = bid >> 8;
  const int t = threadIdx.x, wid = t >> 6, lane = t & 63;
  const int g = lane >> 4, c15 = lane & 15;
  const int qw0 = wid * 32;
  const int nbase = nc * (N_ / NC_);
  constexpr int SS = (N_ / NC_) / 128;

  __shared__ __align__(16) uint16_t kst[2][128][40];
  __shared__ __align__(16) uint16_t vst[2][32][136];
  __shared__ __align__(16) uint16_t plds[8][32][40];

  const uint16_t* Qp = Qb + (size_t)(b * H_ + h) * Q_ * D_;
  bf16x8 qfr[2];
#pragma unroll
  for (int qf = 0; qf < 2; ++qf)
    qfr[qf] = *reinterpret_cast<const bf16x8*>(Qp + (size_t)(qw0 + qf * 16 + c15) * D_ + g * 8);

  f32x4 acc[2][2];
  const f32x4 zero4 = {0.f, 0.f, 0.f, 0.f};
#pragma unroll
  for (int qf = 0; qf < 2; ++qf)
#pragma unroll
    for (int dvf = 0; dvf < 2; ++dvf) acc[qf][dvf] = zero4;
  float lsum[2][4] = {};

  const uint32_t* mrow = mb + (size_t)b * Q_ * (N_ / 32);

  const int krow = t >> 2, kch = t & 3;
  const uint16_t* ksrc = Kh + ((size_t)(b * H_ + h) * N_ + nbase + krow) * 32 + kch * 8;
  const int vrow = t >> 4, vch = t & 15;
  const uint16_t* vsrc = Vh + ((size_t)(b * H_ + h) * 32 + vrow) * N_ + nbase + vch * 8;

  uint4 kreg = *(const uint4*)ksrc;
  uint4 vreg = *(const uint4*)vsrc;

  int cur = 0;
  for (int ss = 0; ss < SS; ++ss) {
    *(uint4*)&kst[cur][krow][kch * 8] = kreg;
    *(uint4*)&vst[cur][vrow][vch * 8] = vreg;
    if (ss < SS - 1) {
      kreg = *(const uint4*)(ksrc + (size_t)(ss + 1) * 128 * 32);
      vreg = *(const uint4*)(vsrc + (ss + 1) * 128);
    }
    lgkm0_barrier();

    const int nstart = nbase + ss * 128;
#pragma unroll
    for (int half = 0; half < 2; ++half) {
      uint32_t mw[2][4][2];
#pragma unroll
      for (int qf = 0; qf < 2; ++qf)
#pragma unroll
        for (int j = 0; j < 4; ++j) {
          const int q = qw0 + qf * 16 + 4 * g + j;
          const uint2 u = *reinterpret_cast<const uint2*>(
              &mrow[(size_t)q * (N_ / 32) + (nstart >> 5) + half * 2]);
          mw[qf][j][0] = u.x;
          mw[qf][j][1] = u.y;
        }
#pragma unroll
      for (int s2 = 0; s2 < 2; ++s2) {
        const int sub = half * 2 + s2;
        const int nl0 = sub * 32;
        bf16x8 kfr[2];
#pragma unroll
        for (int nf = 0; nf < 2; ++nf)
          kfr[nf] = *reinterpret_cast<const bf16x8*>(&kst[cur][nl0 + nf * 16 + c15][g * 8]);
        f32x4 s[2][2];
#pragma unroll
        for (int qf = 0; qf < 2; ++qf)
#pragma unroll
          for (int nf = 0; nf < 2; ++nf)
            s[qf][nf] = __builtin_amdgcn_mfma_f32_16x16x32_bf16(qfr[qf], kfr[nf], zero4, 0, 0, 0);

#pragma unroll
        for (int qf = 0; qf < 2; ++qf) {
#pragma unroll
          for (int j = 0; j < 4; ++j) {
            const uint32_t wmask = mw[qf][j][s2];
#pragma unroll
            for (int nf = 0; nf < 2; ++nf) {
              const int bit = nf * 16 + c15;
              const float p = ((wmask >> bit) & 1u) ? 0.0f : exp2f(s[qf][nf][j]);
              lsum[qf][j] += p;
              plds[wid][qf * 16 + 4 * g + j][nf * 16 + c15] = bfbits(p);
            }
          }
        }
        __asm__ volatile("s_waitcnt lgkmcnt(0)" ::: "memory");
#pragma unroll
        for (int qf = 0; qf < 2; ++qf) {
          const bf16x8 pa = *reinterpret_cast<const bf16x8*>(&plds[wid][qf * 16 + c15][g * 8]);
#pragma unroll
          for (int dvf = 0; dvf < 2; ++dvf) {
            const bf16x8 vb =
                *reinterpret_cast<const bf16x8*>(&vst[cur][dvf * 16 + c15][nl0 + g * 8]);
            acc[qf][dvf] = __builtin_amdgcn_mfma_f32_16x16x32_bf16(pa, vb, acc[qf][dvf], 0, 0, 0);
          }
        }
      }
    }
    __builtin_amdgcn_sched_barrier(0);
    cur ^= 1;
  }

#pragma unroll
  for (int qf = 0; qf < 2; ++qf)
#pragma unroll
    for (int j = 0; j < 4; ++j) {
      float v = lsum[qf][j];
      v += __shfl_xor(v, 1, 64);
      v += __shfl_xor(v, 2, 64);
      v += __shfl_xor(v, 4, 64);
      v += __shfl_xor(v, 8, 64);
      lsum[qf][j] = v;
    }

  // Q-major partial stores: ctxp[((bq*H + h)*NC + nc)*D + dv], bq = b*Q + q
#pragma unroll
  for (int qf = 0; qf < 2; ++qf)
#pragma unroll
    for (int dvf = 0; dvf < 2; ++dvf)
#pragma unroll
      for (int j = 0; j < 4; ++j) {
        const int q = qw0 + qf * 16 + 4 * g + j;
        const size_t base = (((size_t)(b * Q_ + q) * H_ + h) * NC_ + nc) * D_;
        ctx_part[base + dvf * 16 + c15] = bfbits(acc[qf][dvf][j]);
      }
  if (c15 == 0) {
#pragma unroll
    for (int qf = 0; qf < 2; ++qf)
#pragma unroll
      for (int j = 0; j < 4; ++j) {
        const int q = qw0 + qf * 16 + 4 * g + j;
        lsum_part[((size_t)(b * Q_ + q) * H_ + h) * NC_ + nc] = lsum[qf][j];
      }
  }
}

// ---------------------------------------------------------------------------
// Kernel 4: combine partials (Q-major, contiguous per row) + out_proj (woT)
// + residual + LayerNorm.  (R17 winner, unchanged)
// ---------------------------------------------------------------------------
__global__ __launch_bounds__(256) void epilogue(const uint16_t* __restrict__ ctx_part,
                                                const float* __restrict__ lsum_part,
                                                const float* __restrict__ queries,
                                                const float* __restrict__ woT,
                                                const float* __restrict__ bo,
                                                const float* __restrict__ gamma,
                                                const float* __restrict__ beta,
                                                float* __restrict__ out) {
  const int bq = blockIdx.x;
  const int t = threadIdx.x;
  const int h = t >> 5, dv = t & 31;
  const uint16_t* crow = ctx_part + (size_t)bq * H_ * NC_ * D_;
  const float* lrow = lsum_part + (size_t)bq * H_ * NC_;
  float cs = 0.f, ls = 0.f;
#pragma unroll 8
  for (int k = 0; k < NC_; ++k) {
    cs += bf2f(crow[((size_t)h * NC_ + k) * D_ + dv]);
    ls += lrow[h * NC_ + k];
  }
  __shared__ float ctxrow[C_];
  ctxrow[t] = cs / ls;
  __syncthreads();
  float acc = bo[t];
#pragma unroll 8
  for (int j = 0; j < C_; ++j) acc = fmaf(ctxrow[j], woT[(size_t)j * C_ + t], acc);
  const float x = queries[(size_t)bq * C_ + t] + acc;
  float s1 = x, s2 = x * x;
  for (int o = 32; o > 0; o >>= 1) {
    s1 += __shfl_down(s1, o, 64);
    s2 += __shfl_down(s2, o, 64);
  }
  __shared__ float r1[4], r2[4];
  if ((t & 63) == 0) { r1[t >> 6] = s1; r2[t >> 6] = s2; }
  __syncthreads();
  const float mu = (r1[0] + r1[1] + r1[2] + r1[3]) * (1.0f / C_);
  const float e2 = (r2[0] + r2[1] + r2[2] + r2[3]) * (1.0f / C_);
  const float var = e2 - mu * mu;
  out[(size_t)bq * C_ + t] = (x - mu) * rsqrtf(var + 1e-5f) * gamma[t] + beta[t];
}

extern "C" void kernel_launch(void* const* d_in, const int* in_sizes, int n_in,
                              void* d_out, int out_size, void* d_ws, size_t ws_size,
                              hipStream_t stream) {
  const float* queries    = (const float*)d_in[0];
  const float* vidfeat    = (const float*)d_in[1];
  const float* vidmask    = (const float*)d_in[2];
  const float* posembed   = (const float*)d_in[3];
  const float* queryembed = (const float*)d_in[4];
  const float* inw        = (const float*)d_in[5];
  const float* inb        = (const float*)d_in[6];
  const float* outw       = (const float*)d_in[7];
  const float* outb       = (const float*)d_in[8];
  const float* gamma      = (const float*)d_in[9];
  const float* beta       = (const float*)d_in[10];
  float* out = (float*)d_out;

  char* ws = (char*)d_ws;
  size_t off = 0;
  uint16_t* Qb   = (uint16_t*)(ws + off); off += (size_t)B_ * H_ * Q_ * D_ * 2;      // 256 KB
  uint16_t* Kh   = (uint16_t*)(ws + off); off += (size_t)B_ * H_ * N_ * D_ * 2;      // 16.78 MB
  uint16_t* Vh   = (uint16_t*)(ws + off); off += (size_t)B_ * H_ * D_ * N_ * 2;      // 16.78 MB
  uint32_t* mb   = (uint32_t*)(ws + off); off += (size_t)B_ * Q_ * (N_ / 32) * 4;    // 1 MB
  uint16_t* wkv  = (uint16_t*)(ws + off); off += (size_t)768 * C_ * 2;               // 384 KB
  float* woT     = (float*)(ws + off);    off += (size_t)C_ * C_ * 4;                // 256 KB
  uint16_t* ctxp = (uint16_t*)(ws + off); off += (size_t)B_ * Q_ * H_ * NC_ * D_ * 2;// 8.39 MB
  float* lsump   = (float*)(ws + off);    off += (size_t)B_ * Q_ * H_ * NC_ * 4;     // 1 MB

  prep<<<dim3(672), dim3(256), 0, stream>>>(inw, outw, vidmask, wkv, woT, mb);
  kvqproj<<<dim3(264), dim3(1024), 0, stream>>>(vidfeat, posembed, queries, queryembed,
                                                wkv, inb, Kh, Vh, Qb);
  attn<<<dim3(B_ * H_ * NC_), dim3(512), 0, stream>>>(Qb, Kh, Vh, mb, ctxp, lsump);
  epilogue<<<dim3(B_ * Q_), dim3(256), 0, stream>>>(ctxp, lsump, queries, woT, outb,
                                                    gamma, beta, out);
}